// Round 5
// baseline (267.053 us; speedup 1.0000x reference)
//
#include <hip/hip_runtime.h>
#include <math.h>

// Problem constants
#define NQ 8192          // points per batch
#define NP 16384         // total points (B*NQ)
#define H_IN 384
#define W_IN 512
#define HH0 96           // conv out H
#define WW0 128          // conv out W
#define HH1 32           // pooled H
#define WW1 42           // pooled W

// ---------------------------------------------------------------------------
// Kernel 1: transpose conv weights (128,3,7,7) -> wT[tap][oc]
// ---------------------------------------------------------------------------
__global__ void transpose_w_kernel(const float* __restrict__ w, float* __restrict__ wT) {
    int idx = blockIdx.x * 256 + threadIdx.x;
    if (idx < 147 * 128) {
        int tap = idx >> 7;
        int oc  = idx & 127;
        wT[idx] = w[oc * 147 + tap];
    }
}

// ---------------------------------------------------------------------------
// Kernel 2: conv 7x7 stride 4 pad 3 + bias + relu, channels-last output
// ---------------------------------------------------------------------------
__global__ __launch_bounds__(256) void conv_kernel(
    const float* __restrict__ frames, const float* __restrict__ wT,
    const float* __restrict__ bias, float* __restrict__ out)
{
    __shared__ float lds[3 * 7 * 260];
    const int bs  = blockIdx.z;
    const int oh  = blockIdx.y;
    const int ow0 = blockIdx.x * 64;
    const int tid = threadIdx.x;

    for (int idx = tid; idx < 3 * 7 * 259; idx += 256) {
        int c   = idx / 1813;
        int rem = idx - c * 1813;
        int kh  = rem / 259;
        int col = rem - kh * 259;
        int gy  = oh * 4 - 3 + kh;
        int gx  = ow0 * 4 - 3 + col;
        float v = 0.0f;
        if (gy >= 0 && gy < H_IN && gx >= 0 && gx < W_IN) {
            float t = frames[((size_t)(bs * 3 + c) * H_IN + gy) * W_IN + gx];
            v = 2.0f * (t / 255.0f) - 1.0f;
        }
        lds[c * 1820 + kh * 260 + col] = v;
    }
    __syncthreads();

    const int oc = tid & 63;
    const int g  = tid >> 6;
    float a0[16], a1[16];
#pragma unroll
    for (int p = 0; p < 16; ++p) { a0[p] = 0.0f; a1[p] = 0.0f; }

#pragma unroll
    for (int c = 0; c < 3; ++c) {
#pragma unroll
        for (int kh = 0; kh < 7; ++kh) {
            const float* row = lds + c * 1820 + kh * 260 + g * 64;
            float w0[7], w1v[7];
#pragma unroll
            for (int kw = 0; kw < 7; ++kw) {
                int tap = (c * 7 + kh) * 7 + kw;
                w0[kw]  = wT[tap * 128 + oc];
                w1v[kw] = wT[tap * 128 + oc + 64];
            }
#pragma unroll
            for (int p = 0; p < 16; ++p) {
                const float4 A  = *(const float4*)(row + p * 4);
                const float4 Bv = *(const float4*)(row + p * 4 + 4);
                float s0 = a0[p], s1 = a1[p];
                s0 = fmaf(A.x,  w0[0], s0);  s1 = fmaf(A.x,  w1v[0], s1);
                s0 = fmaf(A.y,  w0[1], s0);  s1 = fmaf(A.y,  w1v[1], s1);
                s0 = fmaf(A.z,  w0[2], s0);  s1 = fmaf(A.z,  w1v[2], s1);
                s0 = fmaf(A.w,  w0[3], s0);  s1 = fmaf(A.w,  w1v[3], s1);
                s0 = fmaf(Bv.x, w0[4], s0);  s1 = fmaf(Bv.x, w1v[4], s1);
                s0 = fmaf(Bv.y, w0[5], s0);  s1 = fmaf(Bv.y, w1v[5], s1);
                s0 = fmaf(Bv.z, w0[6], s0);  s1 = fmaf(Bv.z, w1v[6], s1);
                a0[p] = s0; a1[p] = s1;
            }
        }
    }

    const float b0  = bias[oc];
    const float b1b = bias[oc + 64];
#pragma unroll
    for (int p = 0; p < 16; ++p) {
        int ow = ow0 + g * 16 + p;
        size_t ob = ((size_t)(bs * HH0 + oh) * WW0 + ow) * 128;
        out[ob + oc]      = fmaxf(a0[p] + b0, 0.0f);
        out[ob + oc + 64] = fmaxf(a1[p] + b1b, 0.0f);
    }
}

// ---------------------------------------------------------------------------
// Kernel 3: 3x3/s3 avg pool, channels-last
// ---------------------------------------------------------------------------
__global__ void pool_kernel(const float* __restrict__ in, float* __restrict__ out) {
    int idx = blockIdx.x * 256 + threadIdx.x;
    if (idx >= 4 * HH1 * WW1 * 128) return;
    int c = idx & 127;
    int r = idx >> 7;
    int px = r % WW1; r /= WW1;
    int py = r % HH1;
    int bs = r / HH1;
    float s = 0.0f;
#pragma unroll
    for (int dy = 0; dy < 3; ++dy)
#pragma unroll
        for (int dx = 0; dx < 3; ++dx)
            s += in[(((size_t)bs * HH0 + py * 3 + dy) * WW0 + px * 3 + dx) * 128 + c];
    out[idx] = s / 9.0f;
}

// ---------------------------------------------------------------------------
// Kernel 4: sample+corr. One wave per (point,map); 512 thr = 4 points.
// ---------------------------------------------------------------------------
__global__ __launch_bounds__(512) void sample_kernel(
    const float* __restrict__ fm, int hh, int ww,
    const float* __restrict__ cur_in, float* __restrict__ corr_out)
{
    __shared__ float smem[4 * 2400];
    const int tid  = threadIdx.x;
    const int wvi  = tid >> 6;                 // 0..7
    const int lane = tid & 63;
    const int ps   = wvi >> 1;                 // point slot 0..3
    const int mp   = wvi & 1;                  // map 0/1
    const int p    = blockIdx.x * 4 + ps;      // global point id
    const int b    = p >> 13;

    float* fl    = smem + ps * 2400;           // [9][132]
    float* ml    = fl + 1188;                  // [9][132]
    float* inv_s = fl + 2376;                  // [18]: 0..8 invf, 9..17 invm

    const float2 pxy = *(const float2*)(cur_in + (size_t)p * 2);
    const float wwm1 = (float)(ww - 1);
    const float hhm1 = (float)(hh - 1);
    const float ix = ((pxy.x * 2.0f - 1.0f) + 1.0f) * 0.5f * wwm1;
    const float iy = ((pxy.y * 2.0f - 1.0f) + 1.0f) * 0.5f * hhm1;
    const float x0 = floorf(ix), y0 = floorf(iy);
    const float fx1 = ix - x0, fx0 = 1.0f - fx1;
    const float fy1 = iy - y0, fy0 = 1.0f - fy1;

    int   cx[4], cy[4];
    float vx[4], vy[4];
#pragma unroll
    for (int j = 0; j < 4; ++j) {
        float xc = x0 + (float)(j - 1);
        vx[j] = (xc >= 0.0f && xc <= wwm1) ? 1.0f : 0.0f;
        cx[j] = (int)fminf(fmaxf(xc, 0.0f), wwm1);
        float yc = y0 + (float)(j - 1);
        vy[j] = (yc >= 0.0f && yc <= hhm1) ? 1.0f : 0.0f;
        cy[j] = (int)fminf(fmaxf(yc, 0.0f), hhm1);
    }
    float cwx[6], cwy[6];
#pragma unroll
    for (int t = 0; t < 3; ++t) {
        cwx[t * 2 + 0] = fx0 * vx[t]; cwx[t * 2 + 1] = fx1 * vx[t + 1];
        cwy[t * 2 + 0] = fy0 * vy[t]; cwy[t * 2 + 1] = fy1 * vy[t + 1];
    }

    // gather this wave's map: 4x4 float2 patch -> 9 window samples in LDS
    {
        const float2* src = (const float2*)fm + (size_t)(b * 2 + mp) * hh * ww * 64;
        float* dst = mp ? ml : fl;
        float2 P[4][4];
#pragma unroll
        for (int j = 0; j < 4; ++j)
#pragma unroll
            for (int i = 0; i < 4; ++i)
                P[j][i] = src[(cy[j] * ww + cx[i]) * 64 + lane];
#pragma unroll
        for (int ky = 0; ky < 3; ++ky)
#pragma unroll
            for (int kx = 0; kx < 3; ++kx) {
                float wA = cwy[ky * 2 + 0] * cwx[kx * 2 + 0];
                float wB = cwy[ky * 2 + 0] * cwx[kx * 2 + 1];
                float wC = cwy[ky * 2 + 1] * cwx[kx * 2 + 0];
                float wD = cwy[ky * 2 + 1] * cwx[kx * 2 + 1];
                float sx = wA * P[ky][kx].x;
                sx = fmaf(wB, P[ky][kx + 1].x, sx);
                sx = fmaf(wC, P[ky + 1][kx].x, sx);
                sx = fmaf(wD, P[ky + 1][kx + 1].x, sx);
                float sy = wA * P[ky][kx].y;
                sy = fmaf(wB, P[ky][kx + 1].y, sy);
                sy = fmaf(wC, P[ky + 1][kx].y, sy);
                sy = fmaf(wD, P[ky + 1][kx + 1].y, sy);
                *(float2*)(dst + (ky * 3 + kx) * 132 + 2 * lane) = make_float2(sx, sy);
            }
    }
    __syncthreads();

    // dots: this wave handles e = mp*64 + lane (0..98 valid)
    const int e = mp * 64 + lane;
    float s = 0.0f;
    {
        const float *rA, *rB;
        if (e < 81)      { rA = fl + (e / 9) * 132; rB = ml + (e % 9) * 132; }
        else if (e < 90) { rA = fl + (e - 81) * 132; rB = rA; }
        else             { int em = e - 90; if (em > 8) em = 8;
                           rA = ml + em * 132; rB = rA; }
#pragma unroll
        for (int c = 0; c < 128; c += 4) {
            float4 a  = *(const float4*)(rA + c);
            float4 bb = *(const float4*)(rB + c);
            s += a.x * bb.x; s += a.y * bb.y; s += a.z * bb.z; s += a.w * bb.w;
        }
    }
    if (e >= 81 && e < 90)      inv_s[e - 81]     = 1.0f / fmaxf(sqrtf(s), 1e-12f);
    else if (e >= 90 && e < 99) inv_s[e - 90 + 9] = 1.0f / fmaxf(sqrtf(s), 1e-12f);
    __syncthreads();

    if (e < 81)
        corr_out[(size_t)p * 81 + e] = s * inv_s[e / 9] * inv_s[9 + e % 9];
}

// ---------------------------------------------------------------------------
// Kernel 5 (v4): MLP + head. 16 points/block (1024 blocks), K-split GEMM.
// Thread = (jslice = tid&31 -> 8 j's, kslice = tid>>5 -> ~10 i's).
// w1 slice lives in registers (zero redundant L2 reads). Two 8-point tiles.
// ---------------------------------------------------------------------------
__global__ __launch_bounds__(256, 2) void mlp_kernel(
    const float* __restrict__ corr, const float* __restrict__ cur_in,
    const float* __restrict__ w1, const float* __restrict__ b1,
    const float* __restrict__ wp, const float* __restrict__ bp,
    const float* __restrict__ wvw, const float* __restrict__ bvv,
    int hh, int ww,
    float* __restrict__ cur_out,
    const float* __restrict__ vis_in, float* __restrict__ vis_out,
    int is_last)
{
    __shared__ float cls_t[81 * 16];             // corr transposed [i][pt]  (5.2 KB)
    __shared__ float wps[256 * 9 + 256];         // wp | wv                  (10.0 KB)
    __shared__ float hred[4 * 8 * 32 * 12];      // [wave][pt][jsl][8j+4pad] (48 KB)
    const int tid    = threadIdx.x;
    const int wvi    = tid >> 6;
    const int lane   = tid & 63;
    const int jsl    = tid & 31;                 // jslice -> j0..j0+7
    const int j0     = jsl * 8;
    const int ksl    = tid >> 5;                 // kslice 0..7
    const int kstart = ksl * 10;
    const int pbase  = blockIdx.x * 16;

    // stage corr transposed (coalesced read)
    for (int idx = tid; idx < 16 * 81; idx += 256) {
        int pt = idx / 81, i = idx - pt * 81;
        cls_t[i * 16 + pt] = corr[(size_t)pbase * 81 + idx];
    }
    for (int idx = tid; idx < 2304; idx += 256) wps[idx] = wp[idx];
    wps[2304 + tid] = wvw[tid];

    // w1 slice -> registers (no redundancy: every thread loads distinct data)
    float w1r[10][8];
#pragma unroll
    for (int ii = 0; ii < 10; ++ii) {
        const float4* wr = (const float4*)(w1 + (kstart + ii) * 256 + j0);
        float4 a = wr[0], b = wr[1];
        w1r[ii][0] = a.x; w1r[ii][1] = a.y; w1r[ii][2] = a.z; w1r[ii][3] = a.w;
        w1r[ii][4] = b.x; w1r[ii][5] = b.y; w1r[ii][6] = b.z; w1r[ii][7] = b.w;
    }
    float w1e[8] = {0, 0, 0, 0, 0, 0, 0, 0};
    if (ksl == 7) {
        const float4* wr = (const float4*)(w1 + 80 * 256 + j0);
        float4 a = wr[0], b = wr[1];
        w1e[0] = a.x; w1e[1] = a.y; w1e[2] = a.z; w1e[3] = a.w;
        w1e[4] = b.x; w1e[5] = b.y; w1e[6] = b.z; w1e[7] = b.w;
    }
    __syncthreads();

    for (int t = 0; t < 2; ++t) {
        const int pt0 = t * 8;
        float h[8][8];
#pragma unroll
        for (int p = 0; p < 8; ++p)
#pragma unroll
            for (int j = 0; j < 8; ++j) h[p][j] = 0.0f;

#pragma unroll
        for (int ii = 0; ii < 10; ++ii) {
            const int i = kstart + ii;
            const float4 cva = *(const float4*)(cls_t + i * 16 + pt0);
            const float4 cvb = *(const float4*)(cls_t + i * 16 + pt0 + 4);
            const float cv[8] = {cva.x, cva.y, cva.z, cva.w,
                                 cvb.x, cvb.y, cvb.z, cvb.w};
#pragma unroll
            for (int p = 0; p < 8; ++p)
#pragma unroll
                for (int j = 0; j < 8; ++j)
                    h[p][j] = fmaf(cv[p], w1r[ii][j], h[p][j]);
        }
        if (ksl == 7) {   // extra i = 80
            const float4 cva = *(const float4*)(cls_t + 80 * 16 + pt0);
            const float4 cvb = *(const float4*)(cls_t + 80 * 16 + pt0 + 4);
            const float cv[8] = {cva.x, cva.y, cva.z, cva.w,
                                 cvb.x, cvb.y, cvb.z, cvb.w};
#pragma unroll
            for (int p = 0; p < 8; ++p)
#pragma unroll
                for (int j = 0; j < 8; ++j)
                    h[p][j] = fmaf(cv[p], w1e[j], h[p][j]);
        }

        // reduce kslice pair within wave (lane bit 5)
#pragma unroll
        for (int p = 0; p < 8; ++p)
#pragma unroll
            for (int j = 0; j < 8; ++j)
                h[p][j] += __shfl_xor(h[p][j], 32);

        if (lane < 32) {
#pragma unroll
            for (int p = 0; p < 8; ++p) {
                float* dst = hred + ((wvi * 8 + p) * 32 + jsl) * 12;
                *(float4*)(dst)     = make_float4(h[p][0], h[p][1], h[p][2], h[p][3]);
                *(float4*)(dst + 4) = make_float4(h[p][4], h[p][5], h[p][6], h[p][7]);
            }
        }
        __syncthreads();

        // cross-wave sum; thread = (pth = tid>>5, jc = tid&31 -> 8 j's)
        const int pth = ksl;
        const int jc  = jsl;
        float hf[8];
#pragma unroll
        for (int j = 0; j < 8; ++j) hf[j] = 0.0f;
#pragma unroll
        for (int w = 0; w < 4; ++w) {
            const float* src = hred + ((w * 8 + pth) * 32 + jc) * 12;
            const float4 a = *(const float4*)(src);
            const float4 b = *(const float4*)(src + 4);
            hf[0] += a.x; hf[1] += a.y; hf[2] += a.z; hf[3] += a.w;
            hf[4] += b.x; hf[5] += b.y; hf[6] += b.z; hf[7] += b.w;
        }

        float pl10[10];
#pragma unroll
        for (int o = 0; o < 10; ++o) pl10[o] = 0.0f;
#pragma unroll
        for (int j = 0; j < 8; ++j) {
            const float hv = fmaxf(hf[j] + b1[jc * 8 + j], 0.0f);
            const float* wr = wps + (jc * 8 + j) * 9;
#pragma unroll
            for (int o = 0; o < 9; ++o) pl10[o] = fmaf(hv, wr[o], pl10[o]);
            pl10[9] = fmaf(hv, wps[2304 + jc * 8 + j], pl10[9]);
        }
        // reduce over jc (lane bits 0..4)
#pragma unroll
        for (int o = 0; o < 10; ++o) {
            pl10[o] += __shfl_xor(pl10[o], 1);
            pl10[o] += __shfl_xor(pl10[o], 2);
            pl10[o] += __shfl_xor(pl10[o], 4);
            pl10[o] += __shfl_xor(pl10[o], 8);
            pl10[o] += __shfl_xor(pl10[o], 16);
        }

        if (jc == 0) {
            const int p = pbase + pt0 + pth;
            float lg[9];
#pragma unroll
            for (int o = 0; o < 9; ++o) lg[o] = pl10[o] + bp[o];
            float mx = lg[0];
#pragma unroll
            for (int o = 1; o < 9; ++o) mx = fmaxf(mx, lg[o]);
            float ex[9], sum = 0.0f;
#pragma unroll
            for (int o = 0; o < 9; ++o) { ex[o] = expf(lg[o] - mx); sum += ex[o]; }
#pragma unroll
            for (int o = 0; o < 9; ++o) ex[o] = ex[o] / sum;

            const float vis = 1.0f / (1.0f + expf(-(pl10[9] + bvv[0])));

            const float wwm1 = (float)(ww - 1);
            const float hhm1 = (float)(hh - 1);
            const float ax = 1.0f / wwm1;
            const float ay = 1.0f / hhm1;
            const float r0 = ex[0] + ex[1] + ex[2];
            const float r2 = ex[6] + ex[7] + ex[8];
            const float c0 = ex[0] + ex[3] + ex[6];
            const float c2 = ex[2] + ex[5] + ex[8];
            const float dx = r0 * (-ax) + r2 * ax;
            const float dy = c0 * (-ay) + c2 * ay;

            const float2 pq = *(const float2*)(cur_in + (size_t)p * 2);
            *(float2*)(cur_out + (size_t)p * 2) = make_float2(pq.x + dx, pq.y + dy);
            vis_out[p] = is_last ? (vis_in[p] + vis) * 0.5f : vis;
        }
        __syncthreads();   // hred reused by next tile
    }
}

// ---------------------------------------------------------------------------
extern "C" void kernel_launch(void* const* d_in, const int* in_sizes, int n_in,
                              void* d_out, int out_size, void* d_ws, size_t ws_size,
                              hipStream_t stream) {
    (void)in_sizes; (void)n_in; (void)out_size; (void)ws_size;
    const float* queries = (const float*)d_in[0];
    const float* frames  = (const float*)d_in[1];
    const float* conv_w  = (const float*)d_in[2];
    const float* conv_b  = (const float*)d_in[3];
    const float* w1      = (const float*)d_in[4];
    const float* b1      = (const float*)d_in[5];
    const float* wp      = (const float*)d_in[6];
    const float* bp      = (const float*)d_in[7];
    const float* wvw     = (const float*)d_in[8];
    const float* bvv     = (const float*)d_in[9];
    float* out = (float*)d_out;

    // ws layout (floats): fm0 | fm1 | wT | cur_ws | vis_ws | corrws (~33.5 MB)
    float* ws     = (float*)d_ws;
    float* fm0    = ws;                         // 6291456
    float* fm1    = fm0 + 6291456;              // 688128
    float* wT     = fm1 + 688128;               // 18816
    float* cur_ws = wT + 18816;                 // 32768
    float* vis_ws = cur_ws + 32768;             // 16384
    float* corrws = vis_ws + 16384;             // 16384*81 = 1327104

    transpose_w_kernel<<<74, 256, 0, stream>>>(conv_w, wT);
    conv_kernel<<<dim3(2, HH0, 4), 256, 0, stream>>>(frames, wT, conv_b, fm0);
    pool_kernel<<<2688, 256, 0, stream>>>(fm0, fm1);

    // level 0: coarse map
    sample_kernel<<<4096, 512, 0, stream>>>(fm1, HH1, WW1, queries, corrws);
    mlp_kernel<<<1024, 256, 0, stream>>>(corrws, queries, w1, b1, wp, bp, wvw, bvv,
                                         HH1, WW1, cur_ws, nullptr, vis_ws, 0);
    // level 1: fine map, final outputs
    sample_kernel<<<4096, 512, 0, stream>>>(fm0, HH0, WW0, cur_ws, corrws);
    mlp_kernel<<<1024, 256, 0, stream>>>(corrws, cur_ws, w1, b1, wp, bp, wvw, bvv,
                                         HH0, WW0, out, vis_ws, out + 32768, 1);
}

// Round 6
// 251.608 us; speedup vs baseline: 1.0614x; 1.0614x over previous
//
#include <hip/hip_runtime.h>
#include <math.h>

// Problem constants
#define NQ 8192          // points per batch
#define NP 16384         // total points (B*NQ)
#define H_IN 384
#define W_IN 512
#define HH0 96           // conv out H
#define WW0 128          // conv out W
#define HH1 32           // pooled H
#define WW1 42           // pooled W

// ---------------------------------------------------------------------------
// Kernel 1: transpose conv weights (128,3,7,7) -> wT[tap][oc]
// ---------------------------------------------------------------------------
__global__ void transpose_w_kernel(const float* __restrict__ w, float* __restrict__ wT) {
    int idx = blockIdx.x * 256 + threadIdx.x;
    if (idx < 147 * 128) {
        int tap = idx >> 7;
        int oc  = idx & 127;
        wT[idx] = w[oc * 147 + tap];
    }
}

// ---------------------------------------------------------------------------
// Kernel 2: conv 7x7 stride 4 pad 3 + bias + relu, channels-last output
// ---------------------------------------------------------------------------
__global__ __launch_bounds__(256) void conv_kernel(
    const float* __restrict__ frames, const float* __restrict__ wT,
    const float* __restrict__ bias, float* __restrict__ out)
{
    __shared__ float lds[3 * 7 * 260];
    const int bs  = blockIdx.z;
    const int oh  = blockIdx.y;
    const int ow0 = blockIdx.x * 64;
    const int tid = threadIdx.x;

    for (int idx = tid; idx < 3 * 7 * 259; idx += 256) {
        int c   = idx / 1813;
        int rem = idx - c * 1813;
        int kh  = rem / 259;
        int col = rem - kh * 259;
        int gy  = oh * 4 - 3 + kh;
        int gx  = ow0 * 4 - 3 + col;
        float v = 0.0f;
        if (gy >= 0 && gy < H_IN && gx >= 0 && gx < W_IN) {
            float t = frames[((size_t)(bs * 3 + c) * H_IN + gy) * W_IN + gx];
            v = 2.0f * (t / 255.0f) - 1.0f;
        }
        lds[c * 1820 + kh * 260 + col] = v;
    }
    __syncthreads();

    const int oc = tid & 63;
    const int g  = tid >> 6;
    float a0[16], a1[16];
#pragma unroll
    for (int p = 0; p < 16; ++p) { a0[p] = 0.0f; a1[p] = 0.0f; }

#pragma unroll
    for (int c = 0; c < 3; ++c) {
#pragma unroll
        for (int kh = 0; kh < 7; ++kh) {
            const float* row = lds + c * 1820 + kh * 260 + g * 64;
            float w0[7], w1v[7];
#pragma unroll
            for (int kw = 0; kw < 7; ++kw) {
                int tap = (c * 7 + kh) * 7 + kw;
                w0[kw]  = wT[tap * 128 + oc];
                w1v[kw] = wT[tap * 128 + oc + 64];
            }
#pragma unroll
            for (int p = 0; p < 16; ++p) {
                const float4 A  = *(const float4*)(row + p * 4);
                const float4 Bv = *(const float4*)(row + p * 4 + 4);
                float s0 = a0[p], s1 = a1[p];
                s0 = fmaf(A.x,  w0[0], s0);  s1 = fmaf(A.x,  w1v[0], s1);
                s0 = fmaf(A.y,  w0[1], s0);  s1 = fmaf(A.y,  w1v[1], s1);
                s0 = fmaf(A.z,  w0[2], s0);  s1 = fmaf(A.z,  w1v[2], s1);
                s0 = fmaf(A.w,  w0[3], s0);  s1 = fmaf(A.w,  w1v[3], s1);
                s0 = fmaf(Bv.x, w0[4], s0);  s1 = fmaf(Bv.x, w1v[4], s1);
                s0 = fmaf(Bv.y, w0[5], s0);  s1 = fmaf(Bv.y, w1v[5], s1);
                s0 = fmaf(Bv.z, w0[6], s0);  s1 = fmaf(Bv.z, w1v[6], s1);
                a0[p] = s0; a1[p] = s1;
            }
        }
    }

    const float b0  = bias[oc];
    const float b1b = bias[oc + 64];
#pragma unroll
    for (int p = 0; p < 16; ++p) {
        int ow = ow0 + g * 16 + p;
        size_t ob = ((size_t)(bs * HH0 + oh) * WW0 + ow) * 128;
        out[ob + oc]      = fmaxf(a0[p] + b0, 0.0f);
        out[ob + oc + 64] = fmaxf(a1[p] + b1b, 0.0f);
    }
}

// ---------------------------------------------------------------------------
// Kernel 3: 3x3/s3 avg pool, channels-last
// ---------------------------------------------------------------------------
__global__ void pool_kernel(const float* __restrict__ in, float* __restrict__ out) {
    int idx = blockIdx.x * 256 + threadIdx.x;
    if (idx >= 4 * HH1 * WW1 * 128) return;
    int c = idx & 127;
    int r = idx >> 7;
    int px = r % WW1; r /= WW1;
    int py = r % HH1;
    int bs = r / HH1;
    float s = 0.0f;
#pragma unroll
    for (int dy = 0; dy < 3; ++dy)
#pragma unroll
        for (int dx = 0; dx < 3; ++dx)
            s += in[(((size_t)bs * HH0 + py * 3 + dy) * WW0 + px * 3 + dx) * 128 + c];
    out[idx] = s / 9.0f;
}

// ---------------------------------------------------------------------------
// Kernel 4: sample+corr. One wave per (point,map); 512 thr = 4 points.
// ---------------------------------------------------------------------------
__global__ __launch_bounds__(512) void sample_kernel(
    const float* __restrict__ fm, int hh, int ww,
    const float* __restrict__ cur_in, float* __restrict__ corr_out)
{
    __shared__ float smem[4 * 2400];
    const int tid  = threadIdx.x;
    const int wvi  = tid >> 6;                 // 0..7
    const int lane = tid & 63;
    const int ps   = wvi >> 1;                 // point slot 0..3
    const int mp   = wvi & 1;                  // map 0/1
    const int p    = blockIdx.x * 4 + ps;      // global point id
    const int b    = p >> 13;

    float* fl    = smem + ps * 2400;           // [9][132]
    float* ml    = fl + 1188;                  // [9][132]
    float* inv_s = fl + 2376;                  // [18]: 0..8 invf, 9..17 invm

    const float2 pxy = *(const float2*)(cur_in + (size_t)p * 2);
    const float wwm1 = (float)(ww - 1);
    const float hhm1 = (float)(hh - 1);
    const float ix = ((pxy.x * 2.0f - 1.0f) + 1.0f) * 0.5f * wwm1;
    const float iy = ((pxy.y * 2.0f - 1.0f) + 1.0f) * 0.5f * hhm1;
    const float x0 = floorf(ix), y0 = floorf(iy);
    const float fx1 = ix - x0, fx0 = 1.0f - fx1;
    const float fy1 = iy - y0, fy0 = 1.0f - fy1;

    int   cx[4], cy[4];
    float vx[4], vy[4];
#pragma unroll
    for (int j = 0; j < 4; ++j) {
        float xc = x0 + (float)(j - 1);
        vx[j] = (xc >= 0.0f && xc <= wwm1) ? 1.0f : 0.0f;
        cx[j] = (int)fminf(fmaxf(xc, 0.0f), wwm1);
        float yc = y0 + (float)(j - 1);
        vy[j] = (yc >= 0.0f && yc <= hhm1) ? 1.0f : 0.0f;
        cy[j] = (int)fminf(fmaxf(yc, 0.0f), hhm1);
    }
    float cwx[6], cwy[6];
#pragma unroll
    for (int t = 0; t < 3; ++t) {
        cwx[t * 2 + 0] = fx0 * vx[t]; cwx[t * 2 + 1] = fx1 * vx[t + 1];
        cwy[t * 2 + 0] = fy0 * vy[t]; cwy[t * 2 + 1] = fy1 * vy[t + 1];
    }

    // gather this wave's map: 4x4 float2 patch -> 9 window samples in LDS
    {
        const float2* src = (const float2*)fm + (size_t)(b * 2 + mp) * hh * ww * 64;
        float* dst = mp ? ml : fl;
        float2 P[4][4];
#pragma unroll
        for (int j = 0; j < 4; ++j)
#pragma unroll
            for (int i = 0; i < 4; ++i)
                P[j][i] = src[(cy[j] * ww + cx[i]) * 64 + lane];
#pragma unroll
        for (int ky = 0; ky < 3; ++ky)
#pragma unroll
            for (int kx = 0; kx < 3; ++kx) {
                float wA = cwy[ky * 2 + 0] * cwx[kx * 2 + 0];
                float wB = cwy[ky * 2 + 0] * cwx[kx * 2 + 1];
                float wC = cwy[ky * 2 + 1] * cwx[kx * 2 + 0];
                float wD = cwy[ky * 2 + 1] * cwx[kx * 2 + 1];
                float sx = wA * P[ky][kx].x;
                sx = fmaf(wB, P[ky][kx + 1].x, sx);
                sx = fmaf(wC, P[ky + 1][kx].x, sx);
                sx = fmaf(wD, P[ky + 1][kx + 1].x, sx);
                float sy = wA * P[ky][kx].y;
                sy = fmaf(wB, P[ky][kx + 1].y, sy);
                sy = fmaf(wC, P[ky + 1][kx].y, sy);
                sy = fmaf(wD, P[ky + 1][kx + 1].y, sy);
                *(float2*)(dst + (ky * 3 + kx) * 132 + 2 * lane) = make_float2(sx, sy);
            }
    }
    __syncthreads();

    // dots: this wave handles e = mp*64 + lane (0..98 valid)
    const int e = mp * 64 + lane;
    float s = 0.0f;
    {
        const float *rA, *rB;
        if (e < 81)      { rA = fl + (e / 9) * 132; rB = ml + (e % 9) * 132; }
        else if (e < 90) { rA = fl + (e - 81) * 132; rB = rA; }
        else             { int em = e - 90; if (em > 8) em = 8;
                           rA = ml + em * 132; rB = rA; }
#pragma unroll
        for (int c = 0; c < 128; c += 4) {
            float4 a  = *(const float4*)(rA + c);
            float4 bb = *(const float4*)(rB + c);
            s += a.x * bb.x; s += a.y * bb.y; s += a.z * bb.z; s += a.w * bb.w;
        }
    }
    if (e >= 81 && e < 90)      inv_s[e - 81]     = 1.0f / fmaxf(sqrtf(s), 1e-12f);
    else if (e >= 90 && e < 99) inv_s[e - 90 + 9] = 1.0f / fmaxf(sqrtf(s), 1e-12f);
    __syncthreads();

    if (e < 81)
        corr_out[(size_t)p * 81 + e] = s * inv_s[e / 9] * inv_s[9 + e % 9];
}

// ---------------------------------------------------------------------------
// Kernel 5 (v5): MLP + head. 16 points/block (1024 blocks).
// Thread = (jg = tid&31 -> 8 consecutive j's, pg = tid>>5 -> 2 points).
// Full K-loop per thread (no k-reduce). w1 streamed from L2 (2 float4/i,
// unroll x3). j-reduce = 5 shuffles. Small LDS, no spill (VGPR ~60).
// ---------------------------------------------------------------------------
__global__ __launch_bounds__(256) void mlp_kernel(
    const float* __restrict__ corr, const float* __restrict__ cur_in,
    const float* __restrict__ w1, const float* __restrict__ b1,
    const float* __restrict__ wp, const float* __restrict__ bp,
    const float* __restrict__ wvw, const float* __restrict__ bvv,
    int hh, int ww,
    float* __restrict__ cur_out,
    const float* __restrict__ vis_in, float* __restrict__ vis_out,
    int is_last)
{
    __shared__ float cls_t[81 * 18];      // corr transposed [i][pt], stride 18 (5.8 KB)
    __shared__ float wps[256 * 9];        // wp rows (9.2 KB)
    __shared__ float wvs[256];            // wv (1 KB)
    const int tid   = threadIdx.x;
    const int jg    = tid & 31;           // j-group -> j = jg*8 .. jg*8+7
    const int pg    = tid >> 5;           // point-pair 0..7
    const int pbase = blockIdx.x * 16;

    // stage corr transposed: read coalesced, write stride-18 (bank-friendly)
    for (int idx = tid; idx < 16 * 81; idx += 256) {
        int pt = idx / 81, i = idx - pt * 81;
        cls_t[i * 18 + pt] = corr[(size_t)pbase * 81 + idx];
    }
    for (int idx = tid; idx < 2304; idx += 256) wps[idx] = wp[idx];
    wvs[tid] = wvw[tid];
    __syncthreads();

    // stage 1: h[2 pts][8 j] over full K=81
    float h0[8], h1[8];
    {
        const float4* bp4 = (const float4*)(b1 + jg * 8);
        float4 ba = bp4[0], bb = bp4[1];
        h0[0] = ba.x; h0[1] = ba.y; h0[2] = ba.z; h0[3] = ba.w;
        h0[4] = bb.x; h0[5] = bb.y; h0[6] = bb.z; h0[7] = bb.w;
#pragma unroll
        for (int j = 0; j < 8; ++j) h1[j] = h0[j];
    }

    const float* wbase = w1 + jg * 8;
    const float* cvbase = cls_t + pg * 2;
    for (int i = 0; i < 81; i += 3) {
        const float4 a0 = *(const float4*)(wbase + (i    ) * 256);
        const float4 a1 = *(const float4*)(wbase + (i    ) * 256 + 4);
        const float4 b0 = *(const float4*)(wbase + (i + 1) * 256);
        const float4 b1q = *(const float4*)(wbase + (i + 1) * 256 + 4);
        const float4 c0 = *(const float4*)(wbase + (i + 2) * 256);
        const float4 c1 = *(const float4*)(wbase + (i + 2) * 256 + 4);
        const float2 cvA = *(const float2*)(cvbase + (i    ) * 18);
        const float2 cvB = *(const float2*)(cvbase + (i + 1) * 18);
        const float2 cvC = *(const float2*)(cvbase + (i + 2) * 18);
        h0[0] = fmaf(cvA.x, a0.x, h0[0]); h1[0] = fmaf(cvA.y, a0.x, h1[0]);
        h0[1] = fmaf(cvA.x, a0.y, h0[1]); h1[1] = fmaf(cvA.y, a0.y, h1[1]);
        h0[2] = fmaf(cvA.x, a0.z, h0[2]); h1[2] = fmaf(cvA.y, a0.z, h1[2]);
        h0[3] = fmaf(cvA.x, a0.w, h0[3]); h1[3] = fmaf(cvA.y, a0.w, h1[3]);
        h0[4] = fmaf(cvA.x, a1.x, h0[4]); h1[4] = fmaf(cvA.y, a1.x, h1[4]);
        h0[5] = fmaf(cvA.x, a1.y, h0[5]); h1[5] = fmaf(cvA.y, a1.y, h1[5]);
        h0[6] = fmaf(cvA.x, a1.z, h0[6]); h1[6] = fmaf(cvA.y, a1.z, h1[6]);
        h0[7] = fmaf(cvA.x, a1.w, h0[7]); h1[7] = fmaf(cvA.y, a1.w, h1[7]);
        h0[0] = fmaf(cvB.x, b0.x, h0[0]); h1[0] = fmaf(cvB.y, b0.x, h1[0]);
        h0[1] = fmaf(cvB.x, b0.y, h0[1]); h1[1] = fmaf(cvB.y, b0.y, h1[1]);
        h0[2] = fmaf(cvB.x, b0.z, h0[2]); h1[2] = fmaf(cvB.y, b0.z, h1[2]);
        h0[3] = fmaf(cvB.x, b0.w, h0[3]); h1[3] = fmaf(cvB.y, b0.w, h1[3]);
        h0[4] = fmaf(cvB.x, b1q.x, h0[4]); h1[4] = fmaf(cvB.y, b1q.x, h1[4]);
        h0[5] = fmaf(cvB.x, b1q.y, h0[5]); h1[5] = fmaf(cvB.y, b1q.y, h1[5]);
        h0[6] = fmaf(cvB.x, b1q.z, h0[6]); h1[6] = fmaf(cvB.y, b1q.z, h1[6]);
        h0[7] = fmaf(cvB.x, b1q.w, h0[7]); h1[7] = fmaf(cvB.y, b1q.w, h1[7]);
        h0[0] = fmaf(cvC.x, c0.x, h0[0]); h1[0] = fmaf(cvC.y, c0.x, h1[0]);
        h0[1] = fmaf(cvC.x, c0.y, h0[1]); h1[1] = fmaf(cvC.y, c0.y, h1[1]);
        h0[2] = fmaf(cvC.x, c0.z, h0[2]); h1[2] = fmaf(cvC.y, c0.z, h1[2]);
        h0[3] = fmaf(cvC.x, c0.w, h0[3]); h1[3] = fmaf(cvC.y, c0.w, h1[3]);
        h0[4] = fmaf(cvC.x, c1.x, h0[4]); h1[4] = fmaf(cvC.y, c1.x, h1[4]);
        h0[5] = fmaf(cvC.x, c1.y, h0[5]); h1[5] = fmaf(cvC.y, c1.y, h1[5]);
        h0[6] = fmaf(cvC.x, c1.z, h0[6]); h1[6] = fmaf(cvC.y, c1.z, h1[6]);
        h0[7] = fmaf(cvC.x, c1.w, h0[7]); h1[7] = fmaf(cvC.y, c1.w, h1[7]);
    }

    // stage 2: per-point 10 outputs, partial over this thread's 8 j's
    float pl0[10], pl1[10];
#pragma unroll
    for (int o = 0; o < 10; ++o) { pl0[o] = 0.0f; pl1[o] = 0.0f; }
#pragma unroll
    for (int j = 0; j < 8; ++j) {
        const float hv0 = fmaxf(h0[j], 0.0f);
        const float hv1 = fmaxf(h1[j], 0.0f);
        const float* wr = wps + (jg * 8 + j) * 9;
#pragma unroll
        for (int o = 0; o < 9; ++o) {
            const float wv = wr[o];
            pl0[o] = fmaf(hv0, wv, pl0[o]);
            pl1[o] = fmaf(hv1, wv, pl1[o]);
        }
        const float wvv = wvs[jg * 8 + j];
        pl0[9] = fmaf(hv0, wvv, pl0[9]);
        pl1[9] = fmaf(hv1, wvv, pl1[9]);
    }
    // reduce over jg = lane bits 0..4
#pragma unroll
    for (int o = 0; o < 10; ++o) {
        pl0[o] += __shfl_xor(pl0[o], 1);  pl1[o] += __shfl_xor(pl1[o], 1);
        pl0[o] += __shfl_xor(pl0[o], 2);  pl1[o] += __shfl_xor(pl1[o], 2);
        pl0[o] += __shfl_xor(pl0[o], 4);  pl1[o] += __shfl_xor(pl1[o], 4);
        pl0[o] += __shfl_xor(pl0[o], 8);  pl1[o] += __shfl_xor(pl1[o], 8);
        pl0[o] += __shfl_xor(pl0[o], 16); pl1[o] += __shfl_xor(pl1[o], 16);
    }

    if (jg == 0) {
        const float wwm1 = (float)(ww - 1);
        const float hhm1 = (float)(hh - 1);
        const float ax = 1.0f / wwm1;
        const float ay = 1.0f / hhm1;
#pragma unroll
        for (int t = 0; t < 2; ++t) {
            const float* fo = t ? pl1 : pl0;
            const int p = pbase + pg * 2 + t;
            float lg[9];
#pragma unroll
            for (int o = 0; o < 9; ++o) lg[o] = fo[o] + bp[o];
            float mx = lg[0];
#pragma unroll
            for (int o = 1; o < 9; ++o) mx = fmaxf(mx, lg[o]);
            float ex[9], sum = 0.0f;
#pragma unroll
            for (int o = 0; o < 9; ++o) { ex[o] = expf(lg[o] - mx); sum += ex[o]; }
#pragma unroll
            for (int o = 0; o < 9; ++o) ex[o] = ex[o] / sum;

            const float vis = 1.0f / (1.0f + expf(-(fo[9] + bvv[0])));

            const float r0 = ex[0] + ex[1] + ex[2];
            const float r2 = ex[6] + ex[7] + ex[8];
            const float c0 = ex[0] + ex[3] + ex[6];
            const float c2 = ex[2] + ex[5] + ex[8];
            const float dx = r0 * (-ax) + r2 * ax;
            const float dy = c0 * (-ay) + c2 * ay;

            const float2 pq = *(const float2*)(cur_in + (size_t)p * 2);
            *(float2*)(cur_out + (size_t)p * 2) = make_float2(pq.x + dx, pq.y + dy);
            vis_out[p] = is_last ? (vis_in[p] + vis) * 0.5f : vis;
        }
    }
}

// ---------------------------------------------------------------------------
extern "C" void kernel_launch(void* const* d_in, const int* in_sizes, int n_in,
                              void* d_out, int out_size, void* d_ws, size_t ws_size,
                              hipStream_t stream) {
    (void)in_sizes; (void)n_in; (void)out_size; (void)ws_size;
    const float* queries = (const float*)d_in[0];
    const float* frames  = (const float*)d_in[1];
    const float* conv_w  = (const float*)d_in[2];
    const float* conv_b  = (const float*)d_in[3];
    const float* w1      = (const float*)d_in[4];
    const float* b1      = (const float*)d_in[5];
    const float* wp      = (const float*)d_in[6];
    const float* bp      = (const float*)d_in[7];
    const float* wvw     = (const float*)d_in[8];
    const float* bvv     = (const float*)d_in[9];
    float* out = (float*)d_out;

    // ws layout (floats): fm0 | fm1 | wT | cur_ws | vis_ws | corrws (~33.5 MB)
    float* ws     = (float*)d_ws;
    float* fm0    = ws;                         // 6291456
    float* fm1    = fm0 + 6291456;              // 688128
    float* wT     = fm1 + 688128;               // 18816
    float* cur_ws = wT + 18816;                 // 32768
    float* vis_ws = cur_ws + 32768;             // 16384
    float* corrws = vis_ws + 16384;             // 16384*81 = 1327104

    transpose_w_kernel<<<74, 256, 0, stream>>>(conv_w, wT);
    conv_kernel<<<dim3(2, HH0, 4), 256, 0, stream>>>(frames, wT, conv_b, fm0);
    pool_kernel<<<2688, 256, 0, stream>>>(fm0, fm1);

    // level 0: coarse map
    sample_kernel<<<4096, 512, 0, stream>>>(fm1, HH1, WW1, queries, corrws);
    mlp_kernel<<<1024, 256, 0, stream>>>(corrws, queries, w1, b1, wp, bp, wvw, bvv,
                                         HH1, WW1, cur_ws, nullptr, vis_ws, 0);
    // level 1: fine map, final outputs
    sample_kernel<<<4096, 512, 0, stream>>>(fm0, HH0, WW0, cur_ws, corrws);
    mlp_kernel<<<1024, 256, 0, stream>>>(corrws, cur_ws, w1, b1, wp, bp, wvw, bvv,
                                         HH0, WW0, out, vis_ws, out + 32768, 1);
}

// Round 7
// 247.021 us; speedup vs baseline: 1.0811x; 1.0186x over previous
//
#include <hip/hip_runtime.h>
#include <math.h>

// Problem constants
#define NQ 8192          // points per batch
#define NP 16384         // total points (B*NQ)
#define H_IN 384
#define W_IN 512
#define HH0 96           // conv out H
#define WW0 128          // conv out W
#define HH1 32           // pooled H
#define WW1 42           // pooled W

// ---------------------------------------------------------------------------
// Kernel 1: transpose conv weights (128,3,7,7) -> wT[tap][oc]
// ---------------------------------------------------------------------------
__global__ void transpose_w_kernel(const float* __restrict__ w, float* __restrict__ wT) {
    int idx = blockIdx.x * 256 + threadIdx.x;
    if (idx < 147 * 128) {
        int tap = idx >> 7;
        int oc  = idx & 127;
        wT[idx] = w[oc * 147 + tap];
    }
}

// ---------------------------------------------------------------------------
// Kernel 2 (v2): conv 7x7 stride 4 pad 3 + bias + relu, channels-last out.
// Grid (4 ow-tiles of 32, 96 oh, 4 bs) = 1536 blocks (6/CU -> 75% occ cap).
// Wave = 8 pixels x (oc=lane, oc+64). Per (c,kh): shared 36-float row span
// cached in r4[9] registers (9 ds_read_b128, batched) -> 8 px x 14 FMA.
// Accumulation order identical to v1 (c -> kh -> kw): bitwise-same output.
// ---------------------------------------------------------------------------
__global__ __launch_bounds__(256) void conv_kernel(
    const float* __restrict__ frames, const float* __restrict__ wT,
    const float* __restrict__ bias, float* __restrict__ out)
{
    __shared__ float lds[3 * 7 * 136];    // patch [c][kh][col], stride 136
    const int bs  = blockIdx.z;
    const int oh  = blockIdx.y;
    const int ow0 = blockIdx.x * 32;
    const int tid = threadIdx.x;

    // stage input patch: rows oh*4-3+kh, cols ow0*4-3 + [0,134)
    for (int idx = tid; idx < 3 * 7 * 134; idx += 256) {
        int c   = idx / 938;               // 7*134
        int rem = idx - c * 938;
        int kh  = rem / 134;
        int col = rem - kh * 134;
        int gy  = oh * 4 - 3 + kh;
        int gx  = ow0 * 4 - 3 + col;
        float v = 0.0f;
        if (gy >= 0 && gy < H_IN && gx >= 0 && gx < W_IN) {
            float t = frames[((size_t)(bs * 3 + c) * H_IN + gy) * W_IN + gx];
            v = 2.0f * (t / 255.0f) - 1.0f;
        }
        lds[(c * 7 + kh) * 136 + col] = v;
    }
    __syncthreads();

    const int oc = tid & 63;
    const int g  = tid >> 6;                // wave id = pixel octet 0..3
    float a0[8], a1[8];
#pragma unroll
    for (int p = 0; p < 8; ++p) { a0[p] = 0.0f; a1[p] = 0.0f; }

#pragma unroll
    for (int c = 0; c < 3; ++c) {
#pragma unroll
        for (int kh = 0; kh < 7; ++kh) {
            const float* row = lds + (c * 7 + kh) * 136 + g * 32;
            // register row-cache: 9 batched broadcast ds_read_b128
            float4 r4[9];
#pragma unroll
            for (int j = 0; j < 9; ++j) r4[j] = *(const float4*)(row + j * 4);
            float w0[7], w1v[7];
#pragma unroll
            for (int kw = 0; kw < 7; ++kw) {
                int tap = (c * 7 + kh) * 7 + kw;
                w0[kw]  = wT[tap * 128 + oc];
                w1v[kw] = wT[tap * 128 + oc + 64];
            }
#pragma unroll
            for (int p = 0; p < 8; ++p) {
                const float4 A  = r4[p];
                const float4 Bv = r4[p + 1];
                float s0 = a0[p], s1 = a1[p];
                s0 = fmaf(A.x,  w0[0], s0);  s1 = fmaf(A.x,  w1v[0], s1);
                s0 = fmaf(A.y,  w0[1], s0);  s1 = fmaf(A.y,  w1v[1], s1);
                s0 = fmaf(A.z,  w0[2], s0);  s1 = fmaf(A.z,  w1v[2], s1);
                s0 = fmaf(A.w,  w0[3], s0);  s1 = fmaf(A.w,  w1v[3], s1);
                s0 = fmaf(Bv.x, w0[4], s0);  s1 = fmaf(Bv.x, w1v[4], s1);
                s0 = fmaf(Bv.y, w0[5], s0);  s1 = fmaf(Bv.y, w1v[5], s1);
                s0 = fmaf(Bv.z, w0[6], s0);  s1 = fmaf(Bv.z, w1v[6], s1);
                a0[p] = s0; a1[p] = s1;
            }
        }
    }

    const float b0  = bias[oc];
    const float b1b = bias[oc + 64];
#pragma unroll
    for (int p = 0; p < 8; ++p) {
        int ow = ow0 + g * 8 + p;
        size_t ob = ((size_t)(bs * HH0 + oh) * WW0 + ow) * 128;
        out[ob + oc]      = fmaxf(a0[p] + b0, 0.0f);
        out[ob + oc + 64] = fmaxf(a1[p] + b1b, 0.0f);
    }
}

// ---------------------------------------------------------------------------
// Kernel 3: 3x3/s3 avg pool, channels-last
// ---------------------------------------------------------------------------
__global__ void pool_kernel(const float* __restrict__ in, float* __restrict__ out) {
    int idx = blockIdx.x * 256 + threadIdx.x;
    if (idx >= 4 * HH1 * WW1 * 128) return;
    int c = idx & 127;
    int r = idx >> 7;
    int px = r % WW1; r /= WW1;
    int py = r % HH1;
    int bs = r / HH1;
    float s = 0.0f;
#pragma unroll
    for (int dy = 0; dy < 3; ++dy)
#pragma unroll
        for (int dx = 0; dx < 3; ++dx)
            s += in[(((size_t)bs * HH0 + py * 3 + dy) * WW0 + px * 3 + dx) * 128 + c];
    out[idx] = s / 9.0f;
}

// ---------------------------------------------------------------------------
// Kernel 4: sample+corr. One wave per (point,map); 512 thr = 4 points.
// ---------------------------------------------------------------------------
__global__ __launch_bounds__(512) void sample_kernel(
    const float* __restrict__ fm, int hh, int ww,
    const float* __restrict__ cur_in, float* __restrict__ corr_out)
{
    __shared__ float smem[4 * 2400];
    const int tid  = threadIdx.x;
    const int wvi  = tid >> 6;                 // 0..7
    const int lane = tid & 63;
    const int ps   = wvi >> 1;                 // point slot 0..3
    const int mp   = wvi & 1;                  // map 0/1
    const int p    = blockIdx.x * 4 + ps;      // global point id
    const int b    = p >> 13;

    float* fl    = smem + ps * 2400;           // [9][132]
    float* ml    = fl + 1188;                  // [9][132]
    float* inv_s = fl + 2376;                  // [18]: 0..8 invf, 9..17 invm

    const float2 pxy = *(const float2*)(cur_in + (size_t)p * 2);
    const float wwm1 = (float)(ww - 1);
    const float hhm1 = (float)(hh - 1);
    const float ix = ((pxy.x * 2.0f - 1.0f) + 1.0f) * 0.5f * wwm1;
    const float iy = ((pxy.y * 2.0f - 1.0f) + 1.0f) * 0.5f * hhm1;
    const float x0 = floorf(ix), y0 = floorf(iy);
    const float fx1 = ix - x0, fx0 = 1.0f - fx1;
    const float fy1 = iy - y0, fy0 = 1.0f - fy1;

    int   cx[4], cy[4];
    float vx[4], vy[4];
#pragma unroll
    for (int j = 0; j < 4; ++j) {
        float xc = x0 + (float)(j - 1);
        vx[j] = (xc >= 0.0f && xc <= wwm1) ? 1.0f : 0.0f;
        cx[j] = (int)fminf(fmaxf(xc, 0.0f), wwm1);
        float yc = y0 + (float)(j - 1);
        vy[j] = (yc >= 0.0f && yc <= hhm1) ? 1.0f : 0.0f;
        cy[j] = (int)fminf(fmaxf(yc, 0.0f), hhm1);
    }
    float cwx[6], cwy[6];
#pragma unroll
    for (int t = 0; t < 3; ++t) {
        cwx[t * 2 + 0] = fx0 * vx[t]; cwx[t * 2 + 1] = fx1 * vx[t + 1];
        cwy[t * 2 + 0] = fy0 * vy[t]; cwy[t * 2 + 1] = fy1 * vy[t + 1];
    }

    // gather this wave's map: 4x4 float2 patch -> 9 window samples in LDS
    {
        const float2* src = (const float2*)fm + (size_t)(b * 2 + mp) * hh * ww * 64;
        float* dst = mp ? ml : fl;
        float2 P[4][4];
#pragma unroll
        for (int j = 0; j < 4; ++j)
#pragma unroll
            for (int i = 0; i < 4; ++i)
                P[j][i] = src[(cy[j] * ww + cx[i]) * 64 + lane];
#pragma unroll
        for (int ky = 0; ky < 3; ++ky)
#pragma unroll
            for (int kx = 0; kx < 3; ++kx) {
                float wA = cwy[ky * 2 + 0] * cwx[kx * 2 + 0];
                float wB = cwy[ky * 2 + 0] * cwx[kx * 2 + 1];
                float wC = cwy[ky * 2 + 1] * cwx[kx * 2 + 0];
                float wD = cwy[ky * 2 + 1] * cwx[kx * 2 + 1];
                float sx = wA * P[ky][kx].x;
                sx = fmaf(wB, P[ky][kx + 1].x, sx);
                sx = fmaf(wC, P[ky + 1][kx].x, sx);
                sx = fmaf(wD, P[ky + 1][kx + 1].x, sx);
                float sy = wA * P[ky][kx].y;
                sy = fmaf(wB, P[ky][kx + 1].y, sy);
                sy = fmaf(wC, P[ky + 1][kx].y, sy);
                sy = fmaf(wD, P[ky + 1][kx + 1].y, sy);
                *(float2*)(dst + (ky * 3 + kx) * 132 + 2 * lane) = make_float2(sx, sy);
            }
    }
    __syncthreads();

    // dots: this wave handles e = mp*64 + lane (0..98 valid)
    const int e = mp * 64 + lane;
    float s = 0.0f;
    {
        const float *rA, *rB;
        if (e < 81)      { rA = fl + (e / 9) * 132; rB = ml + (e % 9) * 132; }
        else if (e < 90) { rA = fl + (e - 81) * 132; rB = rA; }
        else             { int em = e - 90; if (em > 8) em = 8;
                           rA = ml + em * 132; rB = rA; }
#pragma unroll
        for (int c = 0; c < 128; c += 4) {
            float4 a  = *(const float4*)(rA + c);
            float4 bb = *(const float4*)(rB + c);
            s += a.x * bb.x; s += a.y * bb.y; s += a.z * bb.z; s += a.w * bb.w;
        }
    }
    if (e >= 81 && e < 90)      inv_s[e - 81]     = 1.0f / fmaxf(sqrtf(s), 1e-12f);
    else if (e >= 90 && e < 99) inv_s[e - 90 + 9] = 1.0f / fmaxf(sqrtf(s), 1e-12f);
    __syncthreads();

    if (e < 81)
        corr_out[(size_t)p * 81 + e] = s * inv_s[e / 9] * inv_s[9 + e % 9];
}

// ---------------------------------------------------------------------------
// Kernel 5 (v5): MLP + head. 16 points/block (1024 blocks).
// Thread = (jg = tid&31 -> 8 consecutive j's, pg = tid>>5 -> 2 points).
// Full K-loop per thread (no k-reduce). w1 streamed from L2 (2 float4/i,
// unroll x3). j-reduce = 5 shuffles. Small LDS, no spill (VGPR ~60).
// ---------------------------------------------------------------------------
__global__ __launch_bounds__(256) void mlp_kernel(
    const float* __restrict__ corr, const float* __restrict__ cur_in,
    const float* __restrict__ w1, const float* __restrict__ b1,
    const float* __restrict__ wp, const float* __restrict__ bp,
    const float* __restrict__ wvw, const float* __restrict__ bvv,
    int hh, int ww,
    float* __restrict__ cur_out,
    const float* __restrict__ vis_in, float* __restrict__ vis_out,
    int is_last)
{
    __shared__ float cls_t[81 * 18];      // corr transposed [i][pt], stride 18 (5.8 KB)
    __shared__ float wps[256 * 9];        // wp rows (9.2 KB)
    __shared__ float wvs[256];            // wv (1 KB)
    const int tid   = threadIdx.x;
    const int jg    = tid & 31;           // j-group -> j = jg*8 .. jg*8+7
    const int pg    = tid >> 5;           // point-pair 0..7
    const int pbase = blockIdx.x * 16;

    // stage corr transposed: read coalesced, write stride-18 (bank-friendly)
    for (int idx = tid; idx < 16 * 81; idx += 256) {
        int pt = idx / 81, i = idx - pt * 81;
        cls_t[i * 18 + pt] = corr[(size_t)pbase * 81 + idx];
    }
    for (int idx = tid; idx < 2304; idx += 256) wps[idx] = wp[idx];
    wvs[tid] = wvw[tid];
    __syncthreads();

    // stage 1: h[2 pts][8 j] over full K=81
    float h0[8], h1[8];
    {
        const float4* bp4 = (const float4*)(b1 + jg * 8);
        float4 ba = bp4[0], bb = bp4[1];
        h0[0] = ba.x; h0[1] = ba.y; h0[2] = ba.z; h0[3] = ba.w;
        h0[4] = bb.x; h0[5] = bb.y; h0[6] = bb.z; h0[7] = bb.w;
#pragma unroll
        for (int j = 0; j < 8; ++j) h1[j] = h0[j];
    }

    const float* wbase = w1 + jg * 8;
    const float* cvbase = cls_t + pg * 2;
    for (int i = 0; i < 81; i += 3) {
        const float4 a0 = *(const float4*)(wbase + (i    ) * 256);
        const float4 a1 = *(const float4*)(wbase + (i    ) * 256 + 4);
        const float4 b0 = *(const float4*)(wbase + (i + 1) * 256);
        const float4 b1q = *(const float4*)(wbase + (i + 1) * 256 + 4);
        const float4 c0 = *(const float4*)(wbase + (i + 2) * 256);
        const float4 c1 = *(const float4*)(wbase + (i + 2) * 256 + 4);
        const float2 cvA = *(const float2*)(cvbase + (i    ) * 18);
        const float2 cvB = *(const float2*)(cvbase + (i + 1) * 18);
        const float2 cvC = *(const float2*)(cvbase + (i + 2) * 18);
        h0[0] = fmaf(cvA.x, a0.x, h0[0]); h1[0] = fmaf(cvA.y, a0.x, h1[0]);
        h0[1] = fmaf(cvA.x, a0.y, h0[1]); h1[1] = fmaf(cvA.y, a0.y, h1[1]);
        h0[2] = fmaf(cvA.x, a0.z, h0[2]); h1[2] = fmaf(cvA.y, a0.z, h1[2]);
        h0[3] = fmaf(cvA.x, a0.w, h0[3]); h1[3] = fmaf(cvA.y, a0.w, h1[3]);
        h0[4] = fmaf(cvA.x, a1.x, h0[4]); h1[4] = fmaf(cvA.y, a1.x, h1[4]);
        h0[5] = fmaf(cvA.x, a1.y, h0[5]); h1[5] = fmaf(cvA.y, a1.y, h1[5]);
        h0[6] = fmaf(cvA.x, a1.z, h0[6]); h1[6] = fmaf(cvA.y, a1.z, h1[6]);
        h0[7] = fmaf(cvA.x, a1.w, h0[7]); h1[7] = fmaf(cvA.y, a1.w, h1[7]);
        h0[0] = fmaf(cvB.x, b0.x, h0[0]); h1[0] = fmaf(cvB.y, b0.x, h1[0]);
        h0[1] = fmaf(cvB.x, b0.y, h0[1]); h1[1] = fmaf(cvB.y, b0.y, h1[1]);
        h0[2] = fmaf(cvB.x, b0.z, h0[2]); h1[2] = fmaf(cvB.y, b0.z, h1[2]);
        h0[3] = fmaf(cvB.x, b0.w, h0[3]); h1[3] = fmaf(cvB.y, b0.w, h1[3]);
        h0[4] = fmaf(cvB.x, b1q.x, h0[4]); h1[4] = fmaf(cvB.y, b1q.x, h1[4]);
        h0[5] = fmaf(cvB.x, b1q.y, h0[5]); h1[5] = fmaf(cvB.y, b1q.y, h1[5]);
        h0[6] = fmaf(cvB.x, b1q.z, h0[6]); h1[6] = fmaf(cvB.y, b1q.z, h1[6]);
        h0[7] = fmaf(cvB.x, b1q.w, h0[7]); h1[7] = fmaf(cvB.y, b1q.w, h1[7]);
        h0[0] = fmaf(cvC.x, c0.x, h0[0]); h1[0] = fmaf(cvC.y, c0.x, h1[0]);
        h0[1] = fmaf(cvC.x, c0.y, h0[1]); h1[1] = fmaf(cvC.y, c0.y, h1[1]);
        h0[2] = fmaf(cvC.x, c0.z, h0[2]); h1[2] = fmaf(cvC.y, c0.z, h1[2]);
        h0[3] = fmaf(cvC.x, c0.w, h0[3]); h1[3] = fmaf(cvC.y, c0.w, h1[3]);
        h0[4] = fmaf(cvC.x, c1.x, h0[4]); h1[4] = fmaf(cvC.y, c1.x, h1[4]);
        h0[5] = fmaf(cvC.x, c1.y, h0[5]); h1[5] = fmaf(cvC.y, c1.y, h1[5]);
        h0[6] = fmaf(cvC.x, c1.z, h0[6]); h1[6] = fmaf(cvC.y, c1.z, h1[6]);
        h0[7] = fmaf(cvC.x, c1.w, h0[7]); h1[7] = fmaf(cvC.y, c1.w, h1[7]);
    }

    // stage 2: per-point 10 outputs, partial over this thread's 8 j's
    float pl0[10], pl1[10];
#pragma unroll
    for (int o = 0; o < 10; ++o) { pl0[o] = 0.0f; pl1[o] = 0.0f; }
#pragma unroll
    for (int j = 0; j < 8; ++j) {
        const float hv0 = fmaxf(h0[j], 0.0f);
        const float hv1 = fmaxf(h1[j], 0.0f);
        const float* wr = wps + (jg * 8 + j) * 9;
#pragma unroll
        for (int o = 0; o < 9; ++o) {
            const float wv = wr[o];
            pl0[o] = fmaf(hv0, wv, pl0[o]);
            pl1[o] = fmaf(hv1, wv, pl1[o]);
        }
        const float wvv = wvs[jg * 8 + j];
        pl0[9] = fmaf(hv0, wvv, pl0[9]);
        pl1[9] = fmaf(hv1, wvv, pl1[9]);
    }
    // reduce over jg = lane bits 0..4
#pragma unroll
    for (int o = 0; o < 10; ++o) {
        pl0[o] += __shfl_xor(pl0[o], 1);  pl1[o] += __shfl_xor(pl1[o], 1);
        pl0[o] += __shfl_xor(pl0[o], 2);  pl1[o] += __shfl_xor(pl1[o], 2);
        pl0[o] += __shfl_xor(pl0[o], 4);  pl1[o] += __shfl_xor(pl1[o], 4);
        pl0[o] += __shfl_xor(pl0[o], 8);  pl1[o] += __shfl_xor(pl1[o], 8);
        pl0[o] += __shfl_xor(pl0[o], 16); pl1[o] += __shfl_xor(pl1[o], 16);
    }

    if (jg == 0) {
        const float wwm1 = (float)(ww - 1);
        const float hhm1 = (float)(hh - 1);
        const float ax = 1.0f / wwm1;
        const float ay = 1.0f / hhm1;
#pragma unroll
        for (int t = 0; t < 2; ++t) {
            const float* fo = t ? pl1 : pl0;
            const int p = pbase + pg * 2 + t;
            float lg[9];
#pragma unroll
            for (int o = 0; o < 9; ++o) lg[o] = fo[o] + bp[o];
            float mx = lg[0];
#pragma unroll
            for (int o = 1; o < 9; ++o) mx = fmaxf(mx, lg[o]);
            float ex[9], sum = 0.0f;
#pragma unroll
            for (int o = 0; o < 9; ++o) { ex[o] = expf(lg[o] - mx); sum += ex[o]; }
#pragma unroll
            for (int o = 0; o < 9; ++o) ex[o] = ex[o] / sum;

            const float vis = 1.0f / (1.0f + expf(-(fo[9] + bvv[0])));

            const float r0 = ex[0] + ex[1] + ex[2];
            const float r2 = ex[6] + ex[7] + ex[8];
            const float c0 = ex[0] + ex[3] + ex[6];
            const float c2 = ex[2] + ex[5] + ex[8];
            const float dx = r0 * (-ax) + r2 * ax;
            const float dy = c0 * (-ay) + c2 * ay;

            const float2 pq = *(const float2*)(cur_in + (size_t)p * 2);
            *(float2*)(cur_out + (size_t)p * 2) = make_float2(pq.x + dx, pq.y + dy);
            vis_out[p] = is_last ? (vis_in[p] + vis) * 0.5f : vis;
        }
    }
}

// ---------------------------------------------------------------------------
extern "C" void kernel_launch(void* const* d_in, const int* in_sizes, int n_in,
                              void* d_out, int out_size, void* d_ws, size_t ws_size,
                              hipStream_t stream) {
    (void)in_sizes; (void)n_in; (void)out_size; (void)ws_size;
    const float* queries = (const float*)d_in[0];
    const float* frames  = (const float*)d_in[1];
    const float* conv_w  = (const float*)d_in[2];
    const float* conv_b  = (const float*)d_in[3];
    const float* w1      = (const float*)d_in[4];
    const float* b1      = (const float*)d_in[5];
    const float* wp      = (const float*)d_in[6];
    const float* bp      = (const float*)d_in[7];
    const float* wvw     = (const float*)d_in[8];
    const float* bvv     = (const float*)d_in[9];
    float* out = (float*)d_out;

    // ws layout (floats): fm0 | fm1 | wT | cur_ws | vis_ws | corrws (~33.5 MB)
    float* ws     = (float*)d_ws;
    float* fm0    = ws;                         // 6291456
    float* fm1    = fm0 + 6291456;              // 688128
    float* wT     = fm1 + 688128;               // 18816
    float* cur_ws = wT + 18816;                 // 32768
    float* vis_ws = cur_ws + 32768;             // 16384
    float* corrws = vis_ws + 16384;             // 16384*81 = 1327104

    transpose_w_kernel<<<74, 256, 0, stream>>>(conv_w, wT);
    conv_kernel<<<dim3(4, HH0, 4), 256, 0, stream>>>(frames, wT, conv_b, fm0);
    pool_kernel<<<2688, 256, 0, stream>>>(fm0, fm1);

    // level 0: coarse map
    sample_kernel<<<4096, 512, 0, stream>>>(fm1, HH1, WW1, queries, corrws);
    mlp_kernel<<<1024, 256, 0, stream>>>(corrws, queries, w1, b1, wp, bp, wvw, bvv,
                                         HH1, WW1, cur_ws, nullptr, vis_ws, 0);
    // level 1: fine map, final outputs
    sample_kernel<<<4096, 512, 0, stream>>>(fm0, HH0, WW0, cur_ws, corrws);
    mlp_kernel<<<1024, 256, 0, stream>>>(corrws, cur_ws, w1, b1, wp, bp, wvw, bvv,
                                         HH0, WW0, out, vis_ws, out + 32768, 1);
}

// Round 8
// 231.688 us; speedup vs baseline: 1.1526x; 1.0662x over previous
//
#include <hip/hip_runtime.h>
#include <math.h>

// Problem constants
#define NQ 8192          // points per batch
#define NP 16384         // total points (B*NQ)
#define H_IN 384
#define W_IN 512
#define HH0 96           // conv out H
#define WW0 128          // conv out W
#define HH1 32           // pooled H
#define WW1 42           // pooled W

// ---------------------------------------------------------------------------
// Kernel 1: transpose conv weights (128,3,7,7) -> wT[tap][oc]
// ---------------------------------------------------------------------------
__global__ void transpose_w_kernel(const float* __restrict__ w, float* __restrict__ wT) {
    int idx = blockIdx.x * 256 + threadIdx.x;
    if (idx < 147 * 128) {
        int tap = idx >> 7;
        int oc  = idx & 127;
        wT[idx] = w[oc * 147 + tap];
    }
}

// ---------------------------------------------------------------------------
// Kernel 2 (v3): conv 7x7 stride 4 pad 3 + bias + relu, channels-last out.
// __launch_bounds__(256,4): 128-VGPR budget so the compiler can hoist the
// per-(c,kh) wT loads across iterations (R6: VGPR=40 -> latency-chained).
// Accumulation order identical (c -> kh -> kw): bitwise-same output.
// ---------------------------------------------------------------------------
__global__ __launch_bounds__(256, 4) void conv_kernel(
    const float* __restrict__ frames, const float* __restrict__ wT,
    const float* __restrict__ bias, float* __restrict__ out)
{
    __shared__ float lds[3 * 7 * 136];    // patch [c][kh][col], stride 136
    const int bs  = blockIdx.z;
    const int oh  = blockIdx.y;
    const int ow0 = blockIdx.x * 32;
    const int tid = threadIdx.x;

    // stage input patch: rows oh*4-3+kh, cols ow0*4-3 + [0,134)
    for (int idx = tid; idx < 3 * 7 * 134; idx += 256) {
        int c   = idx / 938;               // 7*134
        int rem = idx - c * 938;
        int kh  = rem / 134;
        int col = rem - kh * 134;
        int gy  = oh * 4 - 3 + kh;
        int gx  = ow0 * 4 - 3 + col;
        float v = 0.0f;
        if (gy >= 0 && gy < H_IN && gx >= 0 && gx < W_IN) {
            float t = frames[((size_t)(bs * 3 + c) * H_IN + gy) * W_IN + gx];
            v = 2.0f * (t / 255.0f) - 1.0f;
        }
        lds[(c * 7 + kh) * 136 + col] = v;
    }
    __syncthreads();

    const int oc = tid & 63;
    const int g  = tid >> 6;                // wave id = pixel octet 0..3
    float a0[8], a1[8];
#pragma unroll
    for (int p = 0; p < 8; ++p) { a0[p] = 0.0f; a1[p] = 0.0f; }

#pragma unroll
    for (int c = 0; c < 3; ++c) {
#pragma unroll
        for (int kh = 0; kh < 7; ++kh) {
            const float* row = lds + (c * 7 + kh) * 136 + g * 32;
            // register row-cache: 9 batched broadcast ds_read_b128
            float4 r4[9];
#pragma unroll
            for (int j = 0; j < 9; ++j) r4[j] = *(const float4*)(row + j * 4);
            float w0[7], w1v[7];
#pragma unroll
            for (int kw = 0; kw < 7; ++kw) {
                int tap = (c * 7 + kh) * 7 + kw;
                w0[kw]  = wT[tap * 128 + oc];
                w1v[kw] = wT[tap * 128 + oc + 64];
            }
#pragma unroll
            for (int p = 0; p < 8; ++p) {
                const float4 A  = r4[p];
                const float4 Bv = r4[p + 1];
                float s0 = a0[p], s1 = a1[p];
                s0 = fmaf(A.x,  w0[0], s0);  s1 = fmaf(A.x,  w1v[0], s1);
                s0 = fmaf(A.y,  w0[1], s0);  s1 = fmaf(A.y,  w1v[1], s1);
                s0 = fmaf(A.z,  w0[2], s0);  s1 = fmaf(A.z,  w1v[2], s1);
                s0 = fmaf(A.w,  w0[3], s0);  s1 = fmaf(A.w,  w1v[3], s1);
                s0 = fmaf(Bv.x, w0[4], s0);  s1 = fmaf(Bv.x, w1v[4], s1);
                s0 = fmaf(Bv.y, w0[5], s0);  s1 = fmaf(Bv.y, w1v[5], s1);
                s0 = fmaf(Bv.z, w0[6], s0);  s1 = fmaf(Bv.z, w1v[6], s1);
                a0[p] = s0; a1[p] = s1;
            }
        }
    }

    const float b0  = bias[oc];
    const float b1b = bias[oc + 64];
#pragma unroll
    for (int p = 0; p < 8; ++p) {
        int ow = ow0 + g * 8 + p;
        size_t ob = ((size_t)(bs * HH0 + oh) * WW0 + ow) * 128;
        out[ob + oc]      = fmaxf(a0[p] + b0, 0.0f);
        out[ob + oc + 64] = fmaxf(a1[p] + b1b, 0.0f);
    }
}

// ---------------------------------------------------------------------------
// Kernel 3: 3x3/s3 avg pool, channels-last
// ---------------------------------------------------------------------------
__global__ void pool_kernel(const float* __restrict__ in, float* __restrict__ out) {
    int idx = blockIdx.x * 256 + threadIdx.x;
    if (idx >= 4 * HH1 * WW1 * 128) return;
    int c = idx & 127;
    int r = idx >> 7;
    int px = r % WW1; r /= WW1;
    int py = r % HH1;
    int bs = r / HH1;
    float s = 0.0f;
#pragma unroll
    for (int dy = 0; dy < 3; ++dy)
#pragma unroll
        for (int dx = 0; dx < 3; ++dx)
            s += in[(((size_t)bs * HH0 + py * 3 + dy) * WW0 + px * 3 + dx) * 128 + c];
    out[idx] = s / 9.0f;
}

// ---------------------------------------------------------------------------
// Kernel 4: sample+corr. One wave per (point,map); 512 thr = 4 points.
// ---------------------------------------------------------------------------
__global__ __launch_bounds__(512) void sample_kernel(
    const float* __restrict__ fm, int hh, int ww,
    const float* __restrict__ cur_in, float* __restrict__ corr_out)
{
    __shared__ float smem[4 * 2400];
    const int tid  = threadIdx.x;
    const int wvi  = tid >> 6;                 // 0..7
    const int lane = tid & 63;
    const int ps   = wvi >> 1;                 // point slot 0..3
    const int mp   = wvi & 1;                  // map 0/1
    const int p    = blockIdx.x * 4 + ps;      // global point id
    const int b    = p >> 13;

    float* fl    = smem + ps * 2400;           // [9][132]
    float* ml    = fl + 1188;                  // [9][132]
    float* inv_s = fl + 2376;                  // [18]: 0..8 invf, 9..17 invm

    const float2 pxy = *(const float2*)(cur_in + (size_t)p * 2);
    const float wwm1 = (float)(ww - 1);
    const float hhm1 = (float)(hh - 1);
    const float ix = ((pxy.x * 2.0f - 1.0f) + 1.0f) * 0.5f * wwm1;
    const float iy = ((pxy.y * 2.0f - 1.0f) + 1.0f) * 0.5f * hhm1;
    const float x0 = floorf(ix), y0 = floorf(iy);
    const float fx1 = ix - x0, fx0 = 1.0f - fx1;
    const float fy1 = iy - y0, fy0 = 1.0f - fy1;

    int   cx[4], cy[4];
    float vx[4], vy[4];
#pragma unroll
    for (int j = 0; j < 4; ++j) {
        float xc = x0 + (float)(j - 1);
        vx[j] = (xc >= 0.0f && xc <= wwm1) ? 1.0f : 0.0f;
        cx[j] = (int)fminf(fmaxf(xc, 0.0f), wwm1);
        float yc = y0 + (float)(j - 1);
        vy[j] = (yc >= 0.0f && yc <= hhm1) ? 1.0f : 0.0f;
        cy[j] = (int)fminf(fmaxf(yc, 0.0f), hhm1);
    }
    float cwx[6], cwy[6];
#pragma unroll
    for (int t = 0; t < 3; ++t) {
        cwx[t * 2 + 0] = fx0 * vx[t]; cwx[t * 2 + 1] = fx1 * vx[t + 1];
        cwy[t * 2 + 0] = fy0 * vy[t]; cwy[t * 2 + 1] = fy1 * vy[t + 1];
    }

    // gather this wave's map: 4x4 float2 patch -> 9 window samples in LDS
    {
        const float2* src = (const float2*)fm + (size_t)(b * 2 + mp) * hh * ww * 64;
        float* dst = mp ? ml : fl;
        float2 P[4][4];
#pragma unroll
        for (int j = 0; j < 4; ++j)
#pragma unroll
            for (int i = 0; i < 4; ++i)
                P[j][i] = src[(cy[j] * ww + cx[i]) * 64 + lane];
#pragma unroll
        for (int ky = 0; ky < 3; ++ky)
#pragma unroll
            for (int kx = 0; kx < 3; ++kx) {
                float wA = cwy[ky * 2 + 0] * cwx[kx * 2 + 0];
                float wB = cwy[ky * 2 + 0] * cwx[kx * 2 + 1];
                float wC = cwy[ky * 2 + 1] * cwx[kx * 2 + 0];
                float wD = cwy[ky * 2 + 1] * cwx[kx * 2 + 1];
                float sx = wA * P[ky][kx].x;
                sx = fmaf(wB, P[ky][kx + 1].x, sx);
                sx = fmaf(wC, P[ky + 1][kx].x, sx);
                sx = fmaf(wD, P[ky + 1][kx + 1].x, sx);
                float sy = wA * P[ky][kx].y;
                sy = fmaf(wB, P[ky][kx + 1].y, sy);
                sy = fmaf(wC, P[ky + 1][kx].y, sy);
                sy = fmaf(wD, P[ky + 1][kx + 1].y, sy);
                *(float2*)(dst + (ky * 3 + kx) * 132 + 2 * lane) = make_float2(sx, sy);
            }
    }
    __syncthreads();

    // dots: this wave handles e = mp*64 + lane (0..98 valid)
    const int e = mp * 64 + lane;
    float s = 0.0f;
    {
        const float *rA, *rB;
        if (e < 81)      { rA = fl + (e / 9) * 132; rB = ml + (e % 9) * 132; }
        else if (e < 90) { rA = fl + (e - 81) * 132; rB = rA; }
        else             { int em = e - 90; if (em > 8) em = 8;
                           rA = ml + em * 132; rB = rA; }
#pragma unroll
        for (int c = 0; c < 128; c += 4) {
            float4 a  = *(const float4*)(rA + c);
            float4 bb = *(const float4*)(rB + c);
            s += a.x * bb.x; s += a.y * bb.y; s += a.z * bb.z; s += a.w * bb.w;
        }
    }
    if (e >= 81 && e < 90)      inv_s[e - 81]     = 1.0f / fmaxf(sqrtf(s), 1e-12f);
    else if (e >= 90 && e < 99) inv_s[e - 90 + 9] = 1.0f / fmaxf(sqrtf(s), 1e-12f);
    __syncthreads();

    if (e < 81)
        corr_out[(size_t)p * 81 + e] = s * inv_s[e / 9] * inv_s[9 + e % 9];
}

// ---------------------------------------------------------------------------
// Kernel 5 (v6): MLP + head. 64 points/block (256 blocks), 512 threads.
// w1 staged fully in LDS once per block (83 KB) -> main loop is pure LDS+FMA,
// zero global traffic. Thread = (jg = tid&31 -> 8 j's, pg = tid>>5 -> 4 pts).
// ---------------------------------------------------------------------------
__global__ __launch_bounds__(512) void mlp_kernel(
    const float* __restrict__ corr, const float* __restrict__ cur_in,
    const float* __restrict__ w1, const float* __restrict__ b1,
    const float* __restrict__ wp, const float* __restrict__ bp,
    const float* __restrict__ wvw, const float* __restrict__ bvv,
    int hh, int ww,
    float* __restrict__ cur_out,
    const float* __restrict__ vis_in, float* __restrict__ vis_out,
    int is_last)
{
    __shared__ float w1L[81 * 256];     // 82944 B
    __shared__ float corrL[81 * 68];    // [i][pt], stride 68 (22 KB)
    __shared__ float wpL[256 * 9];      // 9.2 KB
    __shared__ float wvL[256];
    __shared__ float b1L[256];
    const int tid   = threadIdx.x;
    const int jg    = tid & 31;         // -> j0 = jg*8
    const int pg    = tid >> 5;         // 0..15 -> points pg*4..pg*4+3
    const int j0    = jg * 8;
    const int pbase = blockIdx.x * 64;

    // stage w1 (float4 coalesced: 5184 vec4 / 512 thr)
    {
        const float4* src = (const float4*)w1;
        float4*       dst = (float4*)w1L;
        for (int idx = tid; idx < 5184; idx += 512) dst[idx] = src[idx];
    }
    // stage corr transposed [i][pt]
    for (int idx = tid; idx < 64 * 81; idx += 512) {
        int pt = idx / 81, i = idx - pt * 81;
        corrL[i * 68 + pt] = corr[(size_t)pbase * 81 + idx];
    }
    for (int idx = tid; idx < 2304; idx += 512) wpL[idx] = wp[idx];
    if (tid < 256) { wvL[tid] = wvw[tid]; b1L[tid] = b1[tid]; }
    __syncthreads();

    // stage 1: h[4 pts][8 j], K=81, all operands from LDS
    float h[4][8];
#pragma unroll
    for (int j = 0; j < 8; ++j) {
        const float bj = b1L[j0 + j];
#pragma unroll
        for (int p = 0; p < 4; ++p) h[p][j] = bj;
    }

    const float* wlp = w1L + j0;
    const float* cvp = corrL + pg * 4;
#pragma unroll 3
    for (int i = 0; i < 81; ++i) {
        const float4 wa = *(const float4*)(wlp + i * 256);
        const float4 wb = *(const float4*)(wlp + i * 256 + 4);
        const float4 cv = *(const float4*)(cvp + i * 68);
        const float c4[4] = {cv.x, cv.y, cv.z, cv.w};
#pragma unroll
        for (int p = 0; p < 4; ++p) {
            h[p][0] = fmaf(c4[p], wa.x, h[p][0]);
            h[p][1] = fmaf(c4[p], wa.y, h[p][1]);
            h[p][2] = fmaf(c4[p], wa.z, h[p][2]);
            h[p][3] = fmaf(c4[p], wa.w, h[p][3]);
            h[p][4] = fmaf(c4[p], wb.x, h[p][4]);
            h[p][5] = fmaf(c4[p], wb.y, h[p][5]);
            h[p][6] = fmaf(c4[p], wb.z, h[p][6]);
            h[p][7] = fmaf(c4[p], wb.w, h[p][7]);
        }
    }

    // stage 2: per-point 10 outputs, partial over this thread's 8 j's
    float pl[4][10];
#pragma unroll
    for (int p = 0; p < 4; ++p)
#pragma unroll
        for (int o = 0; o < 10; ++o) pl[p][o] = 0.0f;
#pragma unroll
    for (int j = 0; j < 8; ++j) {
        const float* wr = wpL + (j0 + j) * 9;
        const float wvv = wvL[j0 + j];
#pragma unroll
        for (int p = 0; p < 4; ++p) {
            const float hv = fmaxf(h[p][j], 0.0f);
#pragma unroll
            for (int o = 0; o < 9; ++o) pl[p][o] = fmaf(hv, wr[o], pl[p][o]);
            pl[p][9] = fmaf(hv, wvv, pl[p][9]);
        }
    }
    // reduce over jg (lane bits 0..4; pg is constant across these lanes)
#pragma unroll
    for (int p = 0; p < 4; ++p)
#pragma unroll
        for (int o = 0; o < 10; ++o) {
            pl[p][o] += __shfl_xor(pl[p][o], 1);
            pl[p][o] += __shfl_xor(pl[p][o], 2);
            pl[p][o] += __shfl_xor(pl[p][o], 4);
            pl[p][o] += __shfl_xor(pl[p][o], 8);
            pl[p][o] += __shfl_xor(pl[p][o], 16);
        }

    if (jg == 0) {
        const float wwm1 = (float)(ww - 1);
        const float hhm1 = (float)(hh - 1);
        const float ax = 1.0f / wwm1;
        const float ay = 1.0f / hhm1;
#pragma unroll
        for (int t = 0; t < 4; ++t) {
            const float* fo = pl[t];
            const int p = pbase + pg * 4 + t;
            float lg[9];
#pragma unroll
            for (int o = 0; o < 9; ++o) lg[o] = fo[o] + bp[o];
            float mx = lg[0];
#pragma unroll
            for (int o = 1; o < 9; ++o) mx = fmaxf(mx, lg[o]);
            float ex[9], sum = 0.0f;
#pragma unroll
            for (int o = 0; o < 9; ++o) { ex[o] = expf(lg[o] - mx); sum += ex[o]; }
#pragma unroll
            for (int o = 0; o < 9; ++o) ex[o] = ex[o] / sum;

            const float vis = 1.0f / (1.0f + expf(-(fo[9] + bvv[0])));

            const float r0 = ex[0] + ex[1] + ex[2];
            const float r2 = ex[6] + ex[7] + ex[8];
            const float c0 = ex[0] + ex[3] + ex[6];
            const float c2 = ex[2] + ex[5] + ex[8];
            const float dx = r0 * (-ax) + r2 * ax;
            const float dy = c0 * (-ay) + c2 * ay;

            const float2 pq = *(const float2*)(cur_in + (size_t)p * 2);
            *(float2*)(cur_out + (size_t)p * 2) = make_float2(pq.x + dx, pq.y + dy);
            vis_out[p] = is_last ? (vis_in[p] + vis) * 0.5f : vis;
        }
    }
}

// ---------------------------------------------------------------------------
extern "C" void kernel_launch(void* const* d_in, const int* in_sizes, int n_in,
                              void* d_out, int out_size, void* d_ws, size_t ws_size,
                              hipStream_t stream) {
    (void)in_sizes; (void)n_in; (void)out_size; (void)ws_size;
    const float* queries = (const float*)d_in[0];
    const float* frames  = (const float*)d_in[1];
    const float* conv_w  = (const float*)d_in[2];
    const float* conv_b  = (const float*)d_in[3];
    const float* w1      = (const float*)d_in[4];
    const float* b1      = (const float*)d_in[5];
    const float* wp      = (const float*)d_in[6];
    const float* bp      = (const float*)d_in[7];
    const float* wvw     = (const float*)d_in[8];
    const float* bvv     = (const float*)d_in[9];
    float* out = (float*)d_out;

    // ws layout (floats): fm0 | fm1 | wT | cur_ws | vis_ws | corrws (~33.5 MB)
    float* ws     = (float*)d_ws;
    float* fm0    = ws;                         // 6291456
    float* fm1    = fm0 + 6291456;              // 688128
    float* wT     = fm1 + 688128;               // 18816
    float* cur_ws = wT + 18816;                 // 32768
    float* vis_ws = cur_ws + 32768;             // 16384
    float* corrws = vis_ws + 16384;             // 16384*81 = 1327104

    transpose_w_kernel<<<74, 256, 0, stream>>>(conv_w, wT);
    conv_kernel<<<dim3(4, HH0, 4), 256, 0, stream>>>(frames, wT, conv_b, fm0);
    pool_kernel<<<2688, 256, 0, stream>>>(fm0, fm1);

    // level 0: coarse map
    sample_kernel<<<4096, 512, 0, stream>>>(fm1, HH1, WW1, queries, corrws);
    mlp_kernel<<<256, 512, 0, stream>>>(corrws, queries, w1, b1, wp, bp, wvw, bvv,
                                        HH1, WW1, cur_ws, nullptr, vis_ws, 0);
    // level 1: fine map, final outputs
    sample_kernel<<<4096, 512, 0, stream>>>(fm0, HH0, WW0, cur_ws, corrws);
    mlp_kernel<<<256, 512, 0, stream>>>(corrws, cur_ws, w1, b1, wp, bp, wvw, bvv,
                                        HH0, WW0, out, vis_ws, out + 32768, 1);
}

// Round 9
// 225.828 us; speedup vs baseline: 1.1825x; 1.0259x over previous
//
#include <hip/hip_runtime.h>
#include <math.h>

// Problem constants
#define NQ 8192          // points per batch
#define NP 16384         // total points (B*NQ)
#define H_IN 384
#define W_IN 512
#define HH0 96           // conv out H
#define WW0 128          // conv out W
#define HH1 32           // pooled H
#define WW1 42           // pooled W

// ---------------------------------------------------------------------------
// Kernel 1: transpose conv weights (128,3,7,7) -> wT[tap][oc]
// ---------------------------------------------------------------------------
__global__ void transpose_w_kernel(const float* __restrict__ w, float* __restrict__ wT) {
    int idx = blockIdx.x * 256 + threadIdx.x;
    if (idx < 147 * 128) {
        int tap = idx >> 7;
        int oc  = idx & 127;
        wT[idx] = w[oc * 147 + tap];
    }
}

// ---------------------------------------------------------------------------
// Kernel 2 (v3): conv 7x7 stride 4 pad 3 + bias + relu, channels-last out.
// ---------------------------------------------------------------------------
__global__ __launch_bounds__(256, 4) void conv_kernel(
    const float* __restrict__ frames, const float* __restrict__ wT,
    const float* __restrict__ bias, float* __restrict__ out)
{
    __shared__ float lds[3 * 7 * 136];    // patch [c][kh][col], stride 136
    const int bs  = blockIdx.z;
    const int oh  = blockIdx.y;
    const int ow0 = blockIdx.x * 32;
    const int tid = threadIdx.x;

    for (int idx = tid; idx < 3 * 7 * 134; idx += 256) {
        int c   = idx / 938;               // 7*134
        int rem = idx - c * 938;
        int kh  = rem / 134;
        int col = rem - kh * 134;
        int gy  = oh * 4 - 3 + kh;
        int gx  = ow0 * 4 - 3 + col;
        float v = 0.0f;
        if (gy >= 0 && gy < H_IN && gx >= 0 && gx < W_IN) {
            float t = frames[((size_t)(bs * 3 + c) * H_IN + gy) * W_IN + gx];
            v = 2.0f * (t / 255.0f) - 1.0f;
        }
        lds[(c * 7 + kh) * 136 + col] = v;
    }
    __syncthreads();

    const int oc = tid & 63;
    const int g  = tid >> 6;                // wave id = pixel octet 0..3
    float a0[8], a1[8];
#pragma unroll
    for (int p = 0; p < 8; ++p) { a0[p] = 0.0f; a1[p] = 0.0f; }

#pragma unroll
    for (int c = 0; c < 3; ++c) {
#pragma unroll
        for (int kh = 0; kh < 7; ++kh) {
            const float* row = lds + (c * 7 + kh) * 136 + g * 32;
            float4 r4[9];
#pragma unroll
            for (int j = 0; j < 9; ++j) r4[j] = *(const float4*)(row + j * 4);
            float w0[7], w1v[7];
#pragma unroll
            for (int kw = 0; kw < 7; ++kw) {
                int tap = (c * 7 + kh) * 7 + kw;
                w0[kw]  = wT[tap * 128 + oc];
                w1v[kw] = wT[tap * 128 + oc + 64];
            }
#pragma unroll
            for (int p = 0; p < 8; ++p) {
                const float4 A  = r4[p];
                const float4 Bv = r4[p + 1];
                float s0 = a0[p], s1 = a1[p];
                s0 = fmaf(A.x,  w0[0], s0);  s1 = fmaf(A.x,  w1v[0], s1);
                s0 = fmaf(A.y,  w0[1], s0);  s1 = fmaf(A.y,  w1v[1], s1);
                s0 = fmaf(A.z,  w0[2], s0);  s1 = fmaf(A.z,  w1v[2], s1);
                s0 = fmaf(A.w,  w0[3], s0);  s1 = fmaf(A.w,  w1v[3], s1);
                s0 = fmaf(Bv.x, w0[4], s0);  s1 = fmaf(Bv.x, w1v[4], s1);
                s0 = fmaf(Bv.y, w0[5], s0);  s1 = fmaf(Bv.y, w1v[5], s1);
                s0 = fmaf(Bv.z, w0[6], s0);  s1 = fmaf(Bv.z, w1v[6], s1);
                a0[p] = s0; a1[p] = s1;
            }
        }
    }

    const float b0  = bias[oc];
    const float b1b = bias[oc + 64];
#pragma unroll
    for (int p = 0; p < 8; ++p) {
        int ow = ow0 + g * 8 + p;
        size_t ob = ((size_t)(bs * HH0 + oh) * WW0 + ow) * 128;
        out[ob + oc]      = fmaxf(a0[p] + b0, 0.0f);
        out[ob + oc + 64] = fmaxf(a1[p] + b1b, 0.0f);
    }
}

// ---------------------------------------------------------------------------
// Kernel 3: 3x3/s3 avg pool, channels-last
// ---------------------------------------------------------------------------
__global__ void pool_kernel(const float* __restrict__ in, float* __restrict__ out) {
    int idx = blockIdx.x * 256 + threadIdx.x;
    if (idx >= 4 * HH1 * WW1 * 128) return;
    int c = idx & 127;
    int r = idx >> 7;
    int px = r % WW1; r /= WW1;
    int py = r % HH1;
    int bs = r / HH1;
    float s = 0.0f;
#pragma unroll
    for (int dy = 0; dy < 3; ++dy)
#pragma unroll
        for (int dx = 0; dx < 3; ++dx)
            s += in[(((size_t)bs * HH0 + py * 3 + dy) * WW0 + px * 3 + dx) * 128 + c];
    out[idx] = s / 9.0f;
}

// ---------------------------------------------------------------------------
// Kernel 4: sample+corr. One wave per (point,map); 512 thr = 4 points.
// ---------------------------------------------------------------------------
__global__ __launch_bounds__(512) void sample_kernel(
    const float* __restrict__ fm, int hh, int ww,
    const float* __restrict__ cur_in, float* __restrict__ corr_out)
{
    __shared__ float smem[4 * 2400];
    const int tid  = threadIdx.x;
    const int wvi  = tid >> 6;                 // 0..7
    const int lane = tid & 63;
    const int ps   = wvi >> 1;                 // point slot 0..3
    const int mp   = wvi & 1;                  // map 0/1
    const int p    = blockIdx.x * 4 + ps;      // global point id
    const int b    = p >> 13;

    float* fl    = smem + ps * 2400;           // [9][132]
    float* ml    = fl + 1188;                  // [9][132]
    float* inv_s = fl + 2376;                  // [18]: 0..8 invf, 9..17 invm

    const float2 pxy = *(const float2*)(cur_in + (size_t)p * 2);
    const float wwm1 = (float)(ww - 1);
    const float hhm1 = (float)(hh - 1);
    const float ix = ((pxy.x * 2.0f - 1.0f) + 1.0f) * 0.5f * wwm1;
    const float iy = ((pxy.y * 2.0f - 1.0f) + 1.0f) * 0.5f * hhm1;
    const float x0 = floorf(ix), y0 = floorf(iy);
    const float fx1 = ix - x0, fx0 = 1.0f - fx1;
    const float fy1 = iy - y0, fy0 = 1.0f - fy1;

    int   cx[4], cy[4];
    float vx[4], vy[4];
#pragma unroll
    for (int j = 0; j < 4; ++j) {
        float xc = x0 + (float)(j - 1);
        vx[j] = (xc >= 0.0f && xc <= wwm1) ? 1.0f : 0.0f;
        cx[j] = (int)fminf(fmaxf(xc, 0.0f), wwm1);
        float yc = y0 + (float)(j - 1);
        vy[j] = (yc >= 0.0f && yc <= hhm1) ? 1.0f : 0.0f;
        cy[j] = (int)fminf(fmaxf(yc, 0.0f), hhm1);
    }
    float cwx[6], cwy[6];
#pragma unroll
    for (int t = 0; t < 3; ++t) {
        cwx[t * 2 + 0] = fx0 * vx[t]; cwx[t * 2 + 1] = fx1 * vx[t + 1];
        cwy[t * 2 + 0] = fy0 * vy[t]; cwy[t * 2 + 1] = fy1 * vy[t + 1];
    }

    // gather this wave's map: 4x4 float2 patch -> 9 window samples in LDS
    {
        const float2* src = (const float2*)fm + (size_t)(b * 2 + mp) * hh * ww * 64;
        float* dst = mp ? ml : fl;
        float2 P[4][4];
#pragma unroll
        for (int j = 0; j < 4; ++j)
#pragma unroll
            for (int i = 0; i < 4; ++i)
                P[j][i] = src[(cy[j] * ww + cx[i]) * 64 + lane];
#pragma unroll
        for (int ky = 0; ky < 3; ++ky)
#pragma unroll
            for (int kx = 0; kx < 3; ++kx) {
                float wA = cwy[ky * 2 + 0] * cwx[kx * 2 + 0];
                float wB = cwy[ky * 2 + 0] * cwx[kx * 2 + 1];
                float wC = cwy[ky * 2 + 1] * cwx[kx * 2 + 0];
                float wD = cwy[ky * 2 + 1] * cwx[kx * 2 + 1];
                float sx = wA * P[ky][kx].x;
                sx = fmaf(wB, P[ky][kx + 1].x, sx);
                sx = fmaf(wC, P[ky + 1][kx].x, sx);
                sx = fmaf(wD, P[ky + 1][kx + 1].x, sx);
                float sy = wA * P[ky][kx].y;
                sy = fmaf(wB, P[ky][kx + 1].y, sy);
                sy = fmaf(wC, P[ky + 1][kx].y, sy);
                sy = fmaf(wD, P[ky + 1][kx + 1].y, sy);
                *(float2*)(dst + (ky * 3 + kx) * 132 + 2 * lane) = make_float2(sx, sy);
            }
    }
    __syncthreads();

    // dots: this wave handles e = mp*64 + lane (0..98 valid)
    const int e = mp * 64 + lane;
    float s = 0.0f;
    {
        const float *rA, *rB;
        if (e < 81)      { rA = fl + (e / 9) * 132; rB = ml + (e % 9) * 132; }
        else if (e < 90) { rA = fl + (e - 81) * 132; rB = rA; }
        else             { int em = e - 90; if (em > 8) em = 8;
                           rA = ml + em * 132; rB = rA; }
#pragma unroll
        for (int c = 0; c < 128; c += 4) {
            float4 a  = *(const float4*)(rA + c);
            float4 bb = *(const float4*)(rB + c);
            s += a.x * bb.x; s += a.y * bb.y; s += a.z * bb.z; s += a.w * bb.w;
        }
    }
    if (e >= 81 && e < 90)      inv_s[e - 81]     = 1.0f / fmaxf(sqrtf(s), 1e-12f);
    else if (e >= 90 && e < 99) inv_s[e - 90 + 9] = 1.0f / fmaxf(sqrtf(s), 1e-12f);
    __syncthreads();

    if (e < 81)
        corr_out[(size_t)p * 81 + e] = s * inv_s[e / 9] * inv_s[9 + e % 9];
}

// ---------------------------------------------------------------------------
// Kernel 5 (v7): MLP + head. 16 points/block (1024 blocks).
// Thread = (jg = tid>>3 -> 8 consecutive j's, pq = tid&7 -> 2 points).
// The 8 threads sharing a jg are consecutive lanes -> w1 loads hardware-
// deduped; the 4 waves cover disjoint jg octets -> block reads w1 ONCE
// (85 MB total L2, vs v5's 340 MB). No LDS w1 (no conflicts), no spill.
// j-reduce: 3 shuffles (jg = lane bits 3..5) + cross-wave LDS buffer.
// ---------------------------------------------------------------------------
__global__ __launch_bounds__(256) void mlp_kernel(
    const float* __restrict__ corr, const float* __restrict__ cur_in,
    const float* __restrict__ w1, const float* __restrict__ b1,
    const float* __restrict__ wp, const float* __restrict__ bp,
    const float* __restrict__ wvw, const float* __restrict__ bvv,
    int hh, int ww,
    float* __restrict__ cur_out,
    const float* __restrict__ vis_in, float* __restrict__ vis_out,
    int is_last)
{
    __shared__ float cls_t[81 * 18];      // corr transposed [i][pt], stride 18
    __shared__ float wps[256 * 9];        // wp rows
    __shared__ float wvs[256];            // wv
    __shared__ float red[4 * 10 * 16];    // cross-wave partials [w][o][pt]
    const int tid   = threadIdx.x;
    const int jg    = tid >> 3;           // 0..31 -> j0 = jg*8
    const int pq    = tid & 7;            // point pair -> pts 2pq, 2pq+1
    const int j0    = jg * 8;
    const int wvi   = tid >> 6;           // wave 0..3
    const int lane  = tid & 63;
    const int pbase = blockIdx.x * 16;

    // stage corr transposed: read coalesced, write stride-18
    for (int idx = tid; idx < 16 * 81; idx += 256) {
        int pt = idx / 81, i = idx - pt * 81;
        cls_t[i * 18 + pt] = corr[(size_t)pbase * 81 + idx];
    }
    for (int idx = tid; idx < 2304; idx += 256) wps[idx] = wp[idx];
    wvs[tid] = wvw[tid];
    __syncthreads();

    // stage 1: h[2 pts][8 j] over full K=81; w1 streamed (deduped per octet)
    float h0[8], h1[8];
    {
        const float4* bp4 = (const float4*)(b1 + j0);
        float4 ba = bp4[0], bb = bp4[1];
        h0[0] = ba.x; h0[1] = ba.y; h0[2] = ba.z; h0[3] = ba.w;
        h0[4] = bb.x; h0[5] = bb.y; h0[6] = bb.z; h0[7] = bb.w;
#pragma unroll
        for (int j = 0; j < 8; ++j) h1[j] = h0[j];
    }

    const float* wbase  = w1 + j0;
    const float* cvbase = cls_t + pq * 2;
    for (int i = 0; i < 81; i += 3) {
        const float4 a0  = *(const float4*)(wbase + (i    ) * 256);
        const float4 a1  = *(const float4*)(wbase + (i    ) * 256 + 4);
        const float4 b0  = *(const float4*)(wbase + (i + 1) * 256);
        const float4 b1q = *(const float4*)(wbase + (i + 1) * 256 + 4);
        const float4 c0  = *(const float4*)(wbase + (i + 2) * 256);
        const float4 c1  = *(const float4*)(wbase + (i + 2) * 256 + 4);
        const float2 cvA = *(const float2*)(cvbase + (i    ) * 18);
        const float2 cvB = *(const float2*)(cvbase + (i + 1) * 18);
        const float2 cvC = *(const float2*)(cvbase + (i + 2) * 18);
        h0[0] = fmaf(cvA.x, a0.x, h0[0]); h1[0] = fmaf(cvA.y, a0.x, h1[0]);
        h0[1] = fmaf(cvA.x, a0.y, h0[1]); h1[1] = fmaf(cvA.y, a0.y, h1[1]);
        h0[2] = fmaf(cvA.x, a0.z, h0[2]); h1[2] = fmaf(cvA.y, a0.z, h1[2]);
        h0[3] = fmaf(cvA.x, a0.w, h0[3]); h1[3] = fmaf(cvA.y, a0.w, h1[3]);
        h0[4] = fmaf(cvA.x, a1.x, h0[4]); h1[4] = fmaf(cvA.y, a1.x, h1[4]);
        h0[5] = fmaf(cvA.x, a1.y, h0[5]); h1[5] = fmaf(cvA.y, a1.y, h1[5]);
        h0[6] = fmaf(cvA.x, a1.z, h0[6]); h1[6] = fmaf(cvA.y, a1.z, h1[6]);
        h0[7] = fmaf(cvA.x, a1.w, h0[7]); h1[7] = fmaf(cvA.y, a1.w, h1[7]);
        h0[0] = fmaf(cvB.x, b0.x, h0[0]); h1[0] = fmaf(cvB.y, b0.x, h1[0]);
        h0[1] = fmaf(cvB.x, b0.y, h0[1]); h1[1] = fmaf(cvB.y, b0.y, h1[1]);
        h0[2] = fmaf(cvB.x, b0.z, h0[2]); h1[2] = fmaf(cvB.y, b0.z, h1[2]);
        h0[3] = fmaf(cvB.x, b0.w, h0[3]); h1[3] = fmaf(cvB.y, b0.w, h1[3]);
        h0[4] = fmaf(cvB.x, b1q.x, h0[4]); h1[4] = fmaf(cvB.y, b1q.x, h1[4]);
        h0[5] = fmaf(cvB.x, b1q.y, h0[5]); h1[5] = fmaf(cvB.y, b1q.y, h1[5]);
        h0[6] = fmaf(cvB.x, b1q.z, h0[6]); h1[6] = fmaf(cvB.y, b1q.z, h1[6]);
        h0[7] = fmaf(cvB.x, b1q.w, h0[7]); h1[7] = fmaf(cvB.y, b1q.w, h1[7]);
        h0[0] = fmaf(cvC.x, c0.x, h0[0]); h1[0] = fmaf(cvC.y, c0.x, h1[0]);
        h0[1] = fmaf(cvC.x, c0.y, h0[1]); h1[1] = fmaf(cvC.y, c0.y, h1[1]);
        h0[2] = fmaf(cvC.x, c0.z, h0[2]); h1[2] = fmaf(cvC.y, c0.z, h1[2]);
        h0[3] = fmaf(cvC.x, c0.w, h0[3]); h1[3] = fmaf(cvC.y, c0.w, h1[3]);
        h0[4] = fmaf(cvC.x, c1.x, h0[4]); h1[4] = fmaf(cvC.y, c1.x, h1[4]);
        h0[5] = fmaf(cvC.x, c1.y, h0[5]); h1[5] = fmaf(cvC.y, c1.y, h1[5]);
        h0[6] = fmaf(cvC.x, c1.z, h0[6]); h1[6] = fmaf(cvC.y, c1.z, h1[6]);
        h0[7] = fmaf(cvC.x, c1.w, h0[7]); h1[7] = fmaf(cvC.y, c1.w, h1[7]);
    }

    // stage 2: per-point 10 outputs, partial over this thread's 8 j's
    float pl0[10], pl1[10];
#pragma unroll
    for (int o = 0; o < 10; ++o) { pl0[o] = 0.0f; pl1[o] = 0.0f; }
#pragma unroll
    for (int j = 0; j < 8; ++j) {
        const float hv0 = fmaxf(h0[j], 0.0f);
        const float hv1 = fmaxf(h1[j], 0.0f);
        const float* wr = wps + (j0 + j) * 9;
#pragma unroll
        for (int o = 0; o < 9; ++o) {
            const float wv = wr[o];
            pl0[o] = fmaf(hv0, wv, pl0[o]);
            pl1[o] = fmaf(hv1, wv, pl1[o]);
        }
        const float wvv = wvs[j0 + j];
        pl0[9] = fmaf(hv0, wvv, pl0[9]);
        pl1[9] = fmaf(hv1, wvv, pl1[9]);
    }
    // reduce over jg within wave (jg spans lane bits 3..5)
#pragma unroll
    for (int o = 0; o < 10; ++o) {
        pl0[o] += __shfl_xor(pl0[o], 8);  pl1[o] += __shfl_xor(pl1[o], 8);
        pl0[o] += __shfl_xor(pl0[o], 16); pl1[o] += __shfl_xor(pl1[o], 16);
        pl0[o] += __shfl_xor(pl0[o], 32); pl1[o] += __shfl_xor(pl1[o], 32);
    }
    if (lane < 8) {
#pragma unroll
        for (int o = 0; o < 10; ++o) {
            red[(wvi * 10 + o) * 16 + pq * 2]     = pl0[o];
            red[(wvi * 10 + o) * 16 + pq * 2 + 1] = pl1[o];
        }
    }
    __syncthreads();

    if (tid < 16) {
        const int p = pbase + tid;
        float fo[10];
#pragma unroll
        for (int o = 0; o < 10; ++o) {
            float v = red[o * 16 + tid];
            v += red[(10 + o) * 16 + tid];
            v += red[(20 + o) * 16 + tid];
            v += red[(30 + o) * 16 + tid];
            fo[o] = v;
        }
        float lg[9];
#pragma unroll
        for (int o = 0; o < 9; ++o) lg[o] = fo[o] + bp[o];
        float mx = lg[0];
#pragma unroll
        for (int o = 1; o < 9; ++o) mx = fmaxf(mx, lg[o]);
        float ex[9], sum = 0.0f;
#pragma unroll
        for (int o = 0; o < 9; ++o) { ex[o] = expf(lg[o] - mx); sum += ex[o]; }
#pragma unroll
        for (int o = 0; o < 9; ++o) ex[o] = ex[o] / sum;

        const float vis = 1.0f / (1.0f + expf(-(fo[9] + bvv[0])));

        const float wwm1 = (float)(ww - 1);
        const float hhm1 = (float)(hh - 1);
        const float ax = 1.0f / wwm1;
        const float ay = 1.0f / hhm1;
        const float r0 = ex[0] + ex[1] + ex[2];
        const float r2 = ex[6] + ex[7] + ex[8];
        const float c0 = ex[0] + ex[3] + ex[6];
        const float c2 = ex[2] + ex[5] + ex[8];
        const float dx = r0 * (-ax) + r2 * ax;
        const float dy = c0 * (-ay) + c2 * ay;

        const float2 pq2 = *(const float2*)(cur_in + (size_t)p * 2);
        *(float2*)(cur_out + (size_t)p * 2) = make_float2(pq2.x + dx, pq2.y + dy);
        vis_out[p] = is_last ? (vis_in[p] + vis) * 0.5f : vis;
    }
}

// ---------------------------------------------------------------------------
extern "C" void kernel_launch(void* const* d_in, const int* in_sizes, int n_in,
                              void* d_out, int out_size, void* d_ws, size_t ws_size,
                              hipStream_t stream) {
    (void)in_sizes; (void)n_in; (void)out_size; (void)ws_size;
    const float* queries = (const float*)d_in[0];
    const float* frames  = (const float*)d_in[1];
    const float* conv_w  = (const float*)d_in[2];
    const float* conv_b  = (const float*)d_in[3];
    const float* w1      = (const float*)d_in[4];
    const float* b1      = (const float*)d_in[5];
    const float* wp      = (const float*)d_in[6];
    const float* bp      = (const float*)d_in[7];
    const float* wvw     = (const float*)d_in[8];
    const float* bvv     = (const float*)d_in[9];
    float* out = (float*)d_out;

    // ws layout (floats): fm0 | fm1 | wT | cur_ws | vis_ws | corrws (~33.5 MB)
    float* ws     = (float*)d_ws;
    float* fm0    = ws;                         // 6291456
    float* fm1    = fm0 + 6291456;              // 688128
    float* wT     = fm1 + 688128;               // 18816
    float* cur_ws = wT + 18816;                 // 32768
    float* vis_ws = cur_ws + 32768;             // 16384
    float* corrws = vis_ws + 16384;             // 16384*81 = 1327104

    transpose_w_kernel<<<74, 256, 0, stream>>>(conv_w, wT);
    conv_kernel<<<dim3(4, HH0, 4), 256, 0, stream>>>(frames, wT, conv_b, fm0);
    pool_kernel<<<2688, 256, 0, stream>>>(fm0, fm1);

    // level 0: coarse map
    sample_kernel<<<4096, 512, 0, stream>>>(fm1, HH1, WW1, queries, corrws);
    mlp_kernel<<<1024, 256, 0, stream>>>(corrws, queries, w1, b1, wp, bp, wvw, bvv,
                                         HH1, WW1, cur_ws, nullptr, vis_ws, 0);
    // level 1: fine map, final outputs
    sample_kernel<<<4096, 512, 0, stream>>>(fm0, HH0, WW0, cur_ws, corrws);
    mlp_kernel<<<1024, 256, 0, stream>>>(corrws, cur_ws, w1, b1, wp, bp, wvw, bvv,
                                         HH0, WW0, out, vis_ws, out + 32768, 1);
}